// Round 4
// baseline (569.815 us; speedup 1.0000x reference)
//
#include <hip/hip_runtime.h>
#include <hip/hip_bf16.h>
#include <math.h>

#define DEV __device__ __forceinline__

typedef short bf16x8 __attribute__((ext_vector_type(8)));
typedef float f32x4 __attribute__((ext_vector_type(4)));

static const int Nn = 2048;
static const int DIMd = 512;

DEV float bf2f(short u) {
    union { unsigned int i; float f; } c;
    c.i = ((unsigned int)(unsigned short)u) << 16;
    return c.f;
}

DEV short f2bf(float f) {
    union { float f; unsigned int i; } c;
    c.f = f;
    unsigned int u = c.i;
    unsigned int r = (u + 0x7fffu + ((u >> 16) & 1u)) >> 16;
    return (short)r;
}

// async global->LDS, 16B per lane (lane-linear LDS dest required)
DEV void gload16(const short* __restrict__ g, short* l) {
    __builtin_amdgcn_global_load_lds(
        (__attribute__((address_space(1))) void*)g,
        (__attribute__((address_space(3))) void*)l, 16, 0, 0);
}

// ---------------------------------------------------------------------------
// K0: transpose + cast f32 [K][N] -> bf16 [N][K]
// ---------------------------------------------------------------------------
__global__ void k_transpose_cast(const float* __restrict__ src,
                                 short* __restrict__ dst, int K, int N) {
    int o = blockIdx.x * 256 + threadIdx.x;
    if (o >= K * N) return;
    int n = o / K, k = o - n * K;
    dst[o] = f2bf(src[(size_t)k * N + n]);
}

// ---------------------------------------------------------------------------
// K1: row LayerNorm over DIM=512, f32 in -> bf16 out. One wave per row.
// ---------------------------------------------------------------------------
__global__ __launch_bounds__(256) void k_ln(const float* __restrict__ x,
                                            const float* __restrict__ g,
                                            const float* __restrict__ bta,
                                            short* __restrict__ xn) {
    int row = blockIdx.x * 4 + (threadIdx.x >> 6);
    int lane = threadIdx.x & 63;
    const float* xr = x + (size_t)row * DIMd;
    float4 v0 = ((const float4*)xr)[lane * 2];
    float4 v1 = ((const float4*)xr)[lane * 2 + 1];
    float f[8] = {v0.x, v0.y, v0.z, v0.w, v1.x, v1.y, v1.z, v1.w};
    float s = 0.f, sq = 0.f;
#pragma unroll
    for (int t = 0; t < 8; ++t) { s += f[t]; sq += f[t] * f[t]; }
#pragma unroll
    for (int off = 32; off >= 1; off >>= 1) {
        s += __shfl_xor(s, off);
        sq += __shfl_xor(sq, off);
    }
    float mu = s * (1.0f / 512.0f);
    float var = sq * (1.0f / 512.0f) - mu * mu;
    float rs = rsqrtf(var + 1e-5f);
    bf16x8 o;
#pragma unroll
    for (int t = 0; t < 8; ++t) {
        int c = lane * 8 + t;
        o[t] = f2bf((f[t] - mu) * rs * g[c] + bta[c]);
    }
    *(bf16x8*)(xn + (size_t)row * DIMd + lane * 8) = o;
}

// ---------------------------------------------------------------------------
// m97-style 128x128 tile GEMM main loop (A [M][K], B^T [N][K], k-contig).
// ---------------------------------------------------------------------------
DEV void gemm128_loop(const short* __restrict__ A, const short* __restrict__ B,
                      int K, int i0, int n0, int tid,
                      short* As, short* Bs, f32x4 acc[4][4]) {
    const int w = tid >> 6, wr = w >> 1, wc = w & 1;
    const int lane = tid & 63, fr = lane & 15, fq = lane >> 4;
    const int sr = tid >> 3, sc = (tid & 7) * 8;
    for (int k0 = 0; k0 < K; k0 += 64) {
#pragma unroll
        for (int L = 0; L < 4; ++L) {
            gload16(A + (size_t)(i0 + L * 32 + sr) * K + k0 + sc,
                    As + (L * 32 + sr) * 64 + sc);
            gload16(B + (size_t)(n0 + L * 32 + sr) * K + k0 + sc,
                    Bs + (L * 32 + sr) * 64 + sc);
        }
        __syncthreads();
#pragma unroll
        for (int kk = 0; kk < 2; ++kk) {
            bf16x8 af[4], bfr[4];
#pragma unroll
            for (int m = 0; m < 4; ++m)
                af[m] = *(const bf16x8*)(As + (wr * 64 + m * 16 + fr) * 64 + kk * 32 + fq * 8);
#pragma unroll
            for (int n = 0; n < 4; ++n)
                bfr[n] = *(const bf16x8*)(Bs + (wc * 64 + n * 16 + fr) * 64 + kk * 32 + fq * 8);
#pragma unroll
            for (int m = 0; m < 4; ++m)
#pragma unroll
                for (int n = 0; n < 4; ++n)
                    acc[m][n] = __builtin_amdgcn_mfma_f32_16x16x32_bf16(af[m], bfr[n], acc[m][n], 0, 0, 0);
        }
        __syncthreads();
    }
}

// ---------------------------------------------------------------------------
// K2: qkv = xn @ w_qkvT^T. Scatter epilogue into Q, K (k-contig) and Vt.
// ---------------------------------------------------------------------------
__global__ __launch_bounds__(256) void k_qkv(const short* __restrict__ xn,
                                             const short* __restrict__ wT,
                                             short* __restrict__ Q,
                                             short* __restrict__ Kb,
                                             short* __restrict__ Vt) {
    __shared__ short As[128 * 64], Bs[128 * 64];
    int tid = threadIdx.x;
    int i0 = blockIdx.x * 128, n0 = blockIdx.y * 128;
    f32x4 acc[4][4] = {};
    gemm128_loop(xn, wT, DIMd, i0, n0, tid, As, Bs, acc);
    const int w = tid >> 6, wr = w >> 1, wc = w & 1;
    const int lane = tid & 63, fr = lane & 15, fq = lane >> 4;
#pragma unroll
    for (int m = 0; m < 4; ++m) {
#pragma unroll
        for (int n = 0; n < 4; ++n) {
#pragma unroll
            for (int r = 0; r < 4; ++r) {
                int row = i0 + wr * 64 + m * 16 + fq * 4 + r;
                int c = n0 + wc * 64 + n * 16 + fr;
                short hv = f2bf(acc[m][n][r]);
                int b = row >> 11, i = row & 2047;
                int t = c >> 9, rem = c & 511;
                int h = rem >> 6, dd = rem & 63;
                size_t bh = (size_t)(b * 8 + h);
                if (t == 0)      Q [(bh * Nn + i) * 64 + dd] = hv;
                else if (t == 1) Kb[(bh * Nn + i) * 64 + dd] = hv;
                else             Vt[(bh * 64 + dd) * Nn + i] = hv;
            }
        }
    }
}

// ---------------------------------------------------------------------------
// K6: final = out_h @ w_outT^T + b_out. f32 out.
// ---------------------------------------------------------------------------
__global__ __launch_bounds__(256) void k_out(const short* __restrict__ outh,
                                             const short* __restrict__ wT,
                                             const float* __restrict__ bias,
                                             float* __restrict__ out) {
    __shared__ short As[128 * 64], Bs[128 * 64];
    int tid = threadIdx.x;
    int i0 = blockIdx.x * 128, n0 = blockIdx.y * 128;
    f32x4 acc[4][4] = {};
    gemm128_loop(outh, wT, 512, i0, n0, tid, As, Bs, acc);
    const int w = tid >> 6, wr = w >> 1, wc = w & 1;
    const int lane = tid & 63, fr = lane & 15, fq = lane >> 4;
#pragma unroll
    for (int m = 0; m < 4; ++m)
#pragma unroll
        for (int n = 0; n < 4; ++n)
#pragma unroll
            for (int r = 0; r < 4; ++r) {
                int row = i0 + wr * 64 + m * 16 + fq * 4 + r;
                int c = n0 + wc * 64 + n * 16 + fr;
                out[(size_t)row * 512 + c] = acc[m][n][r] + bias[c];
            }
}

// ---------------------------------------------------------------------------
// K3: scores + exact per-row softmax stats. Block = (bh, 32 i-rows), 4 waves
// stripe the j axis (wave w gets cols jt*128 + w*32). Writes raw bf16 S once
// and (m, 1/l) f32 stats per row (flash-style online combine, exact).
// ---------------------------------------------------------------------------
__global__ __launch_bounds__(256) void k_scores_stats(
    const short* __restrict__ Q, const short* __restrict__ Kb,
    short* __restrict__ S, float* __restrict__ mstat, float* __restrict__ lstat,
    int i0, int ICH) {
    int it = blockIdx.x, bh = blockIdx.y;
    int tid = threadIdx.x, w = tid >> 6, lane = tid & 63;
    int fr = lane & 15, fq = lane >> 4;
    int il0 = it * 32;
    const short* qb = Q + ((size_t)bh * Nn + i0 + il0) * 64;
    bf16x8 af[2][2];
#pragma unroll
    for (int m = 0; m < 2; ++m)
#pragma unroll
        for (int kk = 0; kk < 2; ++kk)
            af[m][kk] = *(const bf16x8*)(qb + (m * 16 + fr) * 64 + kk * 32 + fq * 8);
    float rm[2][4], rl[2][4];
#pragma unroll
    for (int m = 0; m < 2; ++m)
#pragma unroll
        for (int r = 0; r < 4; ++r) { rm[m][r] = -1e30f; rl[m][r] = 0.f; }
    __shared__ float wm[4][32], wl[4][32];
    for (int jt = 0; jt < 16; ++jt) {
        int j0 = jt * 128 + w * 32;
        const short* kb = Kb + ((size_t)bh * Nn + j0) * 64;
        f32x4 acc[2][2] = {};
#pragma unroll
        for (int kk = 0; kk < 2; ++kk) {
            bf16x8 bf0 = *(const bf16x8*)(kb + fr * 64 + kk * 32 + fq * 8);
            bf16x8 bf1 = *(const bf16x8*)(kb + (16 + fr) * 64 + kk * 32 + fq * 8);
#pragma unroll
            for (int m = 0; m < 2; ++m) {
                acc[m][0] = __builtin_amdgcn_mfma_f32_16x16x32_bf16(af[m][kk], bf0, acc[m][0], 0, 0, 0);
                acc[m][1] = __builtin_amdgcn_mfma_f32_16x16x32_bf16(af[m][kk], bf1, acc[m][1], 0, 0, 0);
            }
        }
#pragma unroll
        for (int m = 0; m < 2; ++m) {
            int ilr = il0 + m * 16 + fq * 4;
#pragma unroll
            for (int r = 0; r < 4; ++r) {
                short h0 = f2bf(acc[m][0][r] * 0.125f);
                short h1 = f2bf(acc[m][1][r] * 0.125f);
                size_t ro = ((size_t)bh * ICH + ilr + r) * 2048 + j0;
                S[ro + fr] = h0;
                S[ro + 16 + fr] = h1;
                float s0 = bf2f(h0), s1 = bf2f(h1);
                float v = fmaxf(s0, s1);
#pragma unroll
                for (int off = 8; off >= 1; off >>= 1) v = fmaxf(v, __shfl_xor(v, off));
                float te = __expf(s0 - v) + __expf(s1 - v);
#pragma unroll
                for (int off = 8; off >= 1; off >>= 1) te += __shfl_xor(te, off);
                float mn = fmaxf(rm[m][r], v);
                rl[m][r] = rl[m][r] * __expf(rm[m][r] - mn) + te * __expf(v - mn);
                rm[m][r] = mn;
            }
        }
    }
    if (fr == 0) {
#pragma unroll
        for (int m = 0; m < 2; ++m)
#pragma unroll
            for (int r = 0; r < 4; ++r) {
                wm[w][m * 16 + fq * 4 + r] = rm[m][r];
                wl[w][m * 16 + fq * 4 + r] = rl[m][r];
            }
    }
    __syncthreads();
    if (tid < 32) {
        float M = fmaxf(fmaxf(wm[0][tid], wm[1][tid]), fmaxf(wm[2][tid], wm[3][tid]));
        float L = wl[0][tid] * __expf(wm[0][tid] - M) + wl[1][tid] * __expf(wm[1][tid] - M)
                + wl[2][tid] * __expf(wm[2][tid] - M) + wl[3][tid] * __expf(wm[3][tid] - M);
        mstat[(size_t)bh * ICH + il0 + tid] = M;
        lstat[(size_t)bh * ICH + il0 + tid] = 1.0f / L;
    }
}

// ---------------------------------------------------------------------------
// K4: fused softmax-apply + head-mix + head-LN + PV. Block = (b, 16 i-rows),
// 8 waves. Mix phase: thread (ti=tid>>5, jp=tid&31) owns 8 j for one row,
// reads S for all 8 heads, computes P'' in registers, writes swizzled LDS
// A-tile. PV phase: wave g MFMAs A_lds[g] x V[b,g] into acc (K=256/iter).
// ---------------------------------------------------------------------------
__global__ __launch_bounds__(512) void k_mixpv(
    const short* __restrict__ S, const short* __restrict__ Vt,
    const float* __restrict__ mstat, const float* __restrict__ lstat,
    const float* __restrict__ R, const float* __restrict__ rg,
    const float* __restrict__ rb,
    short* __restrict__ outh, int i0, int ICH) {
    __shared__ short A_lds[8 * 16 * 256];  // 64 KB, XOR-swizzled rows
    __shared__ float Rs[64], rgs[8], rbs[8];
    int it = blockIdx.x, b = blockIdx.y;
    int il0 = it * 16;
    int tid = threadIdx.x;
    if (tid < 64) Rs[tid] = R[tid];
    if (tid < 8) { rgs[tid] = rg[tid]; rbs[tid] = rb[tid]; }
    int g = tid >> 6, lane = tid & 63, fr = lane & 15, fq = lane >> 4;
    int ti = tid >> 5, jp = tid & 31;
    float mh[8], ch[8];
#pragma unroll
    for (int h = 0; h < 8; ++h) {
        size_t si = (size_t)(b * 8 + h) * ICH + il0 + ti;
        mh[h] = mstat[si];
        ch[h] = lstat[si];
    }
    const size_t hs = (size_t)ICH * 2048;
    size_t sbase = ((size_t)(b * 8) * ICH + il0 + ti) * 2048 + jp * 8;
    bf16x8 sv[8];
#pragma unroll
    for (int h = 0; h < 8; ++h) sv[h] = *(const bf16x8*)(S + sbase + h * hs);
    f32x4 acc[4] = {};
    __syncthreads();
    const int swm = (ti & 7) << 4;
    const int swr = (fr & 7) << 4;
    for (int jt = 0; jt < 8; ++jt) {
        // ---- mix + LN (all 512 threads) ----
        bf16x8 obv[8];
#pragma unroll
        for (int e = 0; e < 8; ++e) {
            float pv_[8];
#pragma unroll
            for (int h = 0; h < 8; ++h)
                pv_[h] = __expf(bf2f(sv[h][e]) - mh[h]) * ch[h];
            float pp[8];
#pragma unroll
            for (int gg = 0; gg < 8; ++gg) {
                float s = 0.f;
#pragma unroll
                for (int h = 0; h < 8; ++h) s += pv_[h] * Rs[h * 8 + gg];
                pp[gg] = s;
            }
            float mu = 0.f;
#pragma unroll
            for (int gg = 0; gg < 8; ++gg) mu += pp[gg];
            mu *= 0.125f;
            float var = 0.f;
#pragma unroll
            for (int gg = 0; gg < 8; ++gg) { float d = pp[gg] - mu; var += d * d; }
            var *= 0.125f;
            float rs_ = rsqrtf(var + 1e-5f);
#pragma unroll
            for (int gg = 0; gg < 8; ++gg)
                obv[gg][e] = f2bf((pp[gg] - mu) * rs_ * rgs[gg] + rbs[gg]);
        }
#pragma unroll
        for (int gg = 0; gg < 8; ++gg)
            *(bf16x8*)((char*)A_lds + gg * 8192 + ti * 512 + ((jp * 16) ^ swm)) = obv[gg];
        // prefetch next S tile (hides HBM latency under PV)
        if (jt < 7) {
#pragma unroll
            for (int h = 0; h < 8; ++h)
                sv[h] = *(const bf16x8*)(S + sbase + (jt + 1) * 256 + h * hs);
        }
        __syncthreads();
        // ---- PV for this wave's head g ----
        const short* vb = Vt + (size_t)(b * 8 + g) * 64 * 2048 + jt * 256;
#pragma unroll
        for (int kk = 0; kk < 8; ++kk) {
            bf16x8 a = *(const bf16x8*)((char*)A_lds + g * 8192 + fr * 512 +
                                        (((kk * 32 + fq * 8) * 2) ^ swr));
#pragma unroll
            for (int n = 0; n < 4; ++n) {
                bf16x8 bv = *(const bf16x8*)(vb + (size_t)(n * 16 + fr) * 2048 + kk * 32 + fq * 8);
                acc[n] = __builtin_amdgcn_mfma_f32_16x16x32_bf16(a, bv, acc[n], 0, 0, 0);
            }
        }
        __syncthreads();
    }
#pragma unroll
    for (int n = 0; n < 4; ++n)
#pragma unroll
        for (int r = 0; r < 4; ++r)
            outh[((size_t)b * Nn + i0 + il0 + fq * 4 + r) * 512 + g * 64 + n * 16 + fr] =
                f2bf(acc[n][r]);
}

extern "C" void kernel_launch(void* const* d_in, const int* in_sizes, int n_in,
                              void* d_out, int out_size, void* d_ws, size_t ws_size,
                              hipStream_t stream) {
    const float* x      = (const float*)d_in[0];
    const float* ln_g   = (const float*)d_in[1];
    const float* ln_b   = (const float*)d_in[2];
    const float* w_qkv  = (const float*)d_in[3];
    const float* reattn = (const float*)d_in[4];
    const float* rn_g   = (const float*)d_in[5];
    const float* rn_b   = (const float*)d_in[6];
    const float* w_out  = (const float*)d_in[7];
    const float* b_out  = (const float*)d_in[8];
    float* out = (float*)d_out;

    char* ws = (char*)d_ws;
    short* wqkvT = (short*)ws; ws += (size_t)1536 * 512 * 2;
    short* woutT = (short*)ws; ws += (size_t)512 * 512 * 2;
    short* xn    = (short*)ws; ws += (size_t)8192 * 512 * 2;   // dead after k_qkv
    short* Q     = (short*)ws; ws += (size_t)32 * 2048 * 64 * 2;
    short* Kb    = (short*)ws; ws += (size_t)32 * 2048 * 64 * 2;
    short* Vt    = (short*)ws; ws += (size_t)32 * 64 * 2048 * 2;
    short* outh  = (short*)ws; ws += (size_t)8192 * 512 * 2;
    size_t fixed_bytes = (size_t)(ws - (char*)d_ws);
    short* attnC = (short*)ws;
    // stats alias the dead xn region (needs 32*ICH*4*2 <= 256 KB << 8.39 MB)
    float* mstat = (float*)xn;
    float* lstat = mstat + (size_t)32 * 2048;

    int ICH = 1024;
    while (ICH > 64 && fixed_bytes + (size_t)32 * ICH * Nn * 2 > ws_size) ICH >>= 1;

    k_transpose_cast<<<(512 * 1536 + 255) / 256, 256, 0, stream>>>(w_qkv, wqkvT, 512, 1536);
    k_transpose_cast<<<(512 * 512 + 255) / 256, 256, 0, stream>>>(w_out, woutT, 512, 512);
    k_ln<<<8192 / 4, 256, 0, stream>>>(x, ln_g, ln_b, xn);
    k_qkv<<<dim3(8192 / 128, 1536 / 128), 256, 0, stream>>>(xn, wqkvT, Q, Kb, Vt);

    for (int i0 = 0; i0 < Nn; i0 += ICH) {
        k_scores_stats<<<dim3(ICH / 32, 32), 256, 0, stream>>>(Q, Kb, attnC, mstat, lstat, i0, ICH);
        k_mixpv<<<dim3(ICH / 16, 4), 512, 0, stream>>>(attnC, Vt, mstat, lstat,
                                                       reattn, rn_g, rn_b, outh, i0, ICH);
    }

    k_out<<<dim3(8192 / 128, 512 / 128), 256, 0, stream>>>(outh, woutT, b_out, out);
}

// Round 5
// 518.305 us; speedup vs baseline: 1.0994x; 1.0994x over previous
//
#include <hip/hip_runtime.h>
#include <hip/hip_bf16.h>
#include <math.h>

#define DEV __device__ __forceinline__

typedef short bf16x8 __attribute__((ext_vector_type(8)));
typedef float f32x4 __attribute__((ext_vector_type(4)));

static const int Nn = 2048;
static const int DIMd = 512;

DEV float bf2f(short u) {
    union { unsigned int i; float f; } c;
    c.i = ((unsigned int)(unsigned short)u) << 16;
    return c.f;
}

DEV short f2bf(float f) {
    union { float f; unsigned int i; } c;
    c.f = f;
    unsigned int u = c.i;
    unsigned int r = (u + 0x7fffu + ((u >> 16) & 1u)) >> 16;
    return (short)r;
}

// async global->LDS, 16B per lane (lane-linear LDS dest required)
DEV void gload16(const short* __restrict__ g, short* l) {
    __builtin_amdgcn_global_load_lds(
        (__attribute__((address_space(1))) void*)g,
        (__attribute__((address_space(3))) void*)l, 16, 0, 0);
}

// ---------------------------------------------------------------------------
// K0: transpose + cast f32 [K][N] -> bf16 [N][K]
// ---------------------------------------------------------------------------
__global__ void k_transpose_cast(const float* __restrict__ src,
                                 short* __restrict__ dst, int K, int N) {
    int o = blockIdx.x * 256 + threadIdx.x;
    if (o >= K * N) return;
    int n = o / K, k = o - n * K;
    dst[o] = f2bf(src[(size_t)k * N + n]);
}

// ---------------------------------------------------------------------------
// K1: row LayerNorm over DIM=512, f32 in -> bf16 out. One wave per row.
// ---------------------------------------------------------------------------
__global__ __launch_bounds__(256) void k_ln(const float* __restrict__ x,
                                            const float* __restrict__ g,
                                            const float* __restrict__ bta,
                                            short* __restrict__ xn) {
    int row = blockIdx.x * 4 + (threadIdx.x >> 6);
    int lane = threadIdx.x & 63;
    const float* xr = x + (size_t)row * DIMd;
    float4 v0 = ((const float4*)xr)[lane * 2];
    float4 v1 = ((const float4*)xr)[lane * 2 + 1];
    float f[8] = {v0.x, v0.y, v0.z, v0.w, v1.x, v1.y, v1.z, v1.w};
    float s = 0.f, sq = 0.f;
#pragma unroll
    for (int t = 0; t < 8; ++t) { s += f[t]; sq += f[t] * f[t]; }
#pragma unroll
    for (int off = 32; off >= 1; off >>= 1) {
        s += __shfl_xor(s, off);
        sq += __shfl_xor(sq, off);
    }
    float mu = s * (1.0f / 512.0f);
    float var = sq * (1.0f / 512.0f) - mu * mu;
    float rs = rsqrtf(var + 1e-5f);
    bf16x8 o;
#pragma unroll
    for (int t = 0; t < 8; ++t) {
        int c = lane * 8 + t;
        o[t] = f2bf((f[t] - mu) * rs * g[c] + bta[c]);
    }
    *(bf16x8*)(xn + (size_t)row * DIMd + lane * 8) = o;
}

// ---------------------------------------------------------------------------
// m97-style 128x128 tile GEMM main loop (A [M][K], B^T [N][K], k-contig).
// ---------------------------------------------------------------------------
DEV void gemm128_loop(const short* __restrict__ A, const short* __restrict__ B,
                      int K, int i0, int n0, int tid,
                      short* As, short* Bs, f32x4 acc[4][4]) {
    const int w = tid >> 6, wr = w >> 1, wc = w & 1;
    const int lane = tid & 63, fr = lane & 15, fq = lane >> 4;
    const int sr = tid >> 3, sc = (tid & 7) * 8;
    for (int k0 = 0; k0 < K; k0 += 64) {
#pragma unroll
        for (int L = 0; L < 4; ++L) {
            gload16(A + (size_t)(i0 + L * 32 + sr) * K + k0 + sc,
                    As + (L * 32 + sr) * 64 + sc);
            gload16(B + (size_t)(n0 + L * 32 + sr) * K + k0 + sc,
                    Bs + (L * 32 + sr) * 64 + sc);
        }
        __syncthreads();
#pragma unroll
        for (int kk = 0; kk < 2; ++kk) {
            bf16x8 af[4], bfr[4];
#pragma unroll
            for (int m = 0; m < 4; ++m)
                af[m] = *(const bf16x8*)(As + (wr * 64 + m * 16 + fr) * 64 + kk * 32 + fq * 8);
#pragma unroll
            for (int n = 0; n < 4; ++n)
                bfr[n] = *(const bf16x8*)(Bs + (wc * 64 + n * 16 + fr) * 64 + kk * 32 + fq * 8);
#pragma unroll
            for (int m = 0; m < 4; ++m)
#pragma unroll
                for (int n = 0; n < 4; ++n)
                    acc[m][n] = __builtin_amdgcn_mfma_f32_16x16x32_bf16(af[m], bfr[n], acc[m][n], 0, 0, 0);
        }
        __syncthreads();
    }
}

// ---------------------------------------------------------------------------
// K2: qkv = xn @ w_qkvT^T. Scatter epilogue into Q, K (k-contig) and Vt.
// ---------------------------------------------------------------------------
__global__ __launch_bounds__(256) void k_qkv(const short* __restrict__ xn,
                                             const short* __restrict__ wT,
                                             short* __restrict__ Q,
                                             short* __restrict__ Kb,
                                             short* __restrict__ Vt) {
    __shared__ short As[128 * 64], Bs[128 * 64];
    int tid = threadIdx.x;
    int i0 = blockIdx.x * 128, n0 = blockIdx.y * 128;
    f32x4 acc[4][4] = {};
    gemm128_loop(xn, wT, DIMd, i0, n0, tid, As, Bs, acc);
    const int w = tid >> 6, wr = w >> 1, wc = w & 1;
    const int lane = tid & 63, fr = lane & 15, fq = lane >> 4;
#pragma unroll
    for (int m = 0; m < 4; ++m) {
#pragma unroll
        for (int n = 0; n < 4; ++n) {
#pragma unroll
            for (int r = 0; r < 4; ++r) {
                int row = i0 + wr * 64 + m * 16 + fq * 4 + r;
                int c = n0 + wc * 64 + n * 16 + fr;
                short hv = f2bf(acc[m][n][r]);
                int b = row >> 11, i = row & 2047;
                int t = c >> 9, rem = c & 511;
                int h = rem >> 6, dd = rem & 63;
                size_t bh = (size_t)(b * 8 + h);
                if (t == 0)      Q [(bh * Nn + i) * 64 + dd] = hv;
                else if (t == 1) Kb[(bh * Nn + i) * 64 + dd] = hv;
                else             Vt[(bh * 64 + dd) * Nn + i] = hv;
            }
        }
    }
}

// ---------------------------------------------------------------------------
// K6: final = out_h @ w_outT^T + b_out. f32 out.
// ---------------------------------------------------------------------------
__global__ __launch_bounds__(256) void k_out(const short* __restrict__ outh,
                                             const short* __restrict__ wT,
                                             const float* __restrict__ bias,
                                             float* __restrict__ out) {
    __shared__ short As[128 * 64], Bs[128 * 64];
    int tid = threadIdx.x;
    int i0 = blockIdx.x * 128, n0 = blockIdx.y * 128;
    f32x4 acc[4][4] = {};
    gemm128_loop(outh, wT, 512, i0, n0, tid, As, Bs, acc);
    const int w = tid >> 6, wr = w >> 1, wc = w & 1;
    const int lane = tid & 63, fr = lane & 15, fq = lane >> 4;
#pragma unroll
    for (int m = 0; m < 4; ++m)
#pragma unroll
        for (int n = 0; n < 4; ++n)
#pragma unroll
            for (int r = 0; r < 4; ++r) {
                int row = i0 + wr * 64 + m * 16 + fq * 4 + r;
                int c = n0 + wc * 64 + n * 16 + fr;
                out[(size_t)row * 512 + c] = acc[m][n][r] + bias[c];
            }
}

// ---------------------------------------------------------------------------
// K3: scores + exact per-row softmax stats. Block = (bh, 32 i-rows), 4 waves
// stripe the j axis. Writes raw bf16 S once and (m, 1/l) f32 stats per row.
// ---------------------------------------------------------------------------
__global__ __launch_bounds__(256) void k_scores_stats(
    const short* __restrict__ Q, const short* __restrict__ Kb,
    short* __restrict__ S, float* __restrict__ mstat, float* __restrict__ lstat,
    int i0, int ICH) {
    int it = blockIdx.x, bh = blockIdx.y;
    int tid = threadIdx.x, w = tid >> 6, lane = tid & 63;
    int fr = lane & 15, fq = lane >> 4;
    int il0 = it * 32;
    const short* qb = Q + ((size_t)bh * Nn + i0 + il0) * 64;
    bf16x8 af[2][2];
#pragma unroll
    for (int m = 0; m < 2; ++m)
#pragma unroll
        for (int kk = 0; kk < 2; ++kk)
            af[m][kk] = *(const bf16x8*)(qb + (m * 16 + fr) * 64 + kk * 32 + fq * 8);
    float rm[2][4], rl[2][4];
#pragma unroll
    for (int m = 0; m < 2; ++m)
#pragma unroll
        for (int r = 0; r < 4; ++r) { rm[m][r] = -1e30f; rl[m][r] = 0.f; }
    __shared__ float wm[4][32], wl[4][32];
    for (int jt = 0; jt < 16; ++jt) {
        int j0 = jt * 128 + w * 32;
        const short* kb = Kb + ((size_t)bh * Nn + j0) * 64;
        f32x4 acc[2][2] = {};
#pragma unroll
        for (int kk = 0; kk < 2; ++kk) {
            bf16x8 bf0 = *(const bf16x8*)(kb + fr * 64 + kk * 32 + fq * 8);
            bf16x8 bf1 = *(const bf16x8*)(kb + (16 + fr) * 64 + kk * 32 + fq * 8);
#pragma unroll
            for (int m = 0; m < 2; ++m) {
                acc[m][0] = __builtin_amdgcn_mfma_f32_16x16x32_bf16(af[m][kk], bf0, acc[m][0], 0, 0, 0);
                acc[m][1] = __builtin_amdgcn_mfma_f32_16x16x32_bf16(af[m][kk], bf1, acc[m][1], 0, 0, 0);
            }
        }
#pragma unroll
        for (int m = 0; m < 2; ++m) {
            int ilr = il0 + m * 16 + fq * 4;
#pragma unroll
            for (int r = 0; r < 4; ++r) {
                short h0 = f2bf(acc[m][0][r] * 0.125f);
                short h1 = f2bf(acc[m][1][r] * 0.125f);
                size_t ro = ((size_t)bh * ICH + ilr + r) * 2048 + j0;
                S[ro + fr] = h0;
                S[ro + 16 + fr] = h1;
                float s0 = bf2f(h0), s1 = bf2f(h1);
                float v = fmaxf(s0, s1);
#pragma unroll
                for (int off = 8; off >= 1; off >>= 1) v = fmaxf(v, __shfl_xor(v, off));
                float te = __expf(s0 - v) + __expf(s1 - v);
#pragma unroll
                for (int off = 8; off >= 1; off >>= 1) te += __shfl_xor(te, off);
                float mn = fmaxf(rm[m][r], v);
                rl[m][r] = rl[m][r] * __expf(rm[m][r] - mn) + te * __expf(v - mn);
                rm[m][r] = mn;
            }
        }
    }
    if (fr == 0) {
#pragma unroll
        for (int m = 0; m < 2; ++m)
#pragma unroll
            for (int r = 0; r < 4; ++r) {
                wm[w][m * 16 + fq * 4 + r] = rm[m][r];
                wl[w][m * 16 + fq * 4 + r] = rl[m][r];
            }
    }
    __syncthreads();
    if (tid < 32) {
        float M = fmaxf(fmaxf(wm[0][tid], wm[1][tid]), fmaxf(wm[2][tid], wm[3][tid]));
        float L = wl[0][tid] * __expf(wm[0][tid] - M) + wl[1][tid] * __expf(wm[1][tid] - M)
                + wl[2][tid] * __expf(wm[2][tid] - M) + wl[3][tid] * __expf(wm[3][tid] - M);
        mstat[(size_t)bh * ICH + il0 + tid] = M;
        lstat[(size_t)bh * ICH + il0 + tid] = 1.0f / L;
    }
}

// ---------------------------------------------------------------------------
// K4: fused softmax-apply + head-mix + head-LN + PV. Block = (b, 16 i-rows),
// 8 waves, 1 block/CU (launch_bounds min-waves=2 -> 256 VGPR, no spill).
// Mix uses row-centered R' so the LN mean falls out algebraically.
// ---------------------------------------------------------------------------
__global__ __launch_bounds__(512, 2) void k_mixpv(
    const short* __restrict__ S, const short* __restrict__ Vt,
    const float* __restrict__ mstat, const float* __restrict__ lstat,
    const float* __restrict__ R, const float* __restrict__ rg,
    const float* __restrict__ rb,
    short* __restrict__ outh, int i0, int ICH) {
    __shared__ short A_lds[8 * 16 * 256];  // 64 KB, XOR-swizzled rows
    __shared__ float Rraw[64], Rc[64], rgs[8], rbs[8];
    int it = blockIdx.x, b = blockIdx.y;
    int il0 = it * 16;
    int tid = threadIdx.x;
    if (tid < 64) Rraw[tid] = R[tid];
    if (tid < 8) { rgs[tid] = rg[tid]; rbs[tid] = rb[tid]; }
    __syncthreads();
    if (tid < 64) {
        int h = tid >> 3;
        float mn = 0.f;
#pragma unroll
        for (int gg = 0; gg < 8; ++gg) mn += Rraw[h * 8 + gg];
        Rc[tid] = Rraw[tid] - mn * 0.125f;  // centered over g
    }
    int g = tid >> 6, lane = tid & 63, fr = lane & 15, fq = lane >> 4;
    int ti = tid >> 5, jp = tid & 31;
    float mh[8], ch[8];
#pragma unroll
    for (int h = 0; h < 8; ++h) {
        size_t si = (size_t)(b * 8 + h) * ICH + il0 + ti;
        mh[h] = mstat[si];
        ch[h] = lstat[si];
    }
    const size_t hs = (size_t)ICH * 2048;
    size_t sbase = ((size_t)(b * 8) * ICH + il0 + ti) * 2048 + jp * 8;
    bf16x8 sv[8];
#pragma unroll
    for (int h = 0; h < 8; ++h) sv[h] = *(const bf16x8*)(S + sbase + h * hs);
    f32x4 acc[4] = {};
    __syncthreads();
    const int swm = (ti & 7) << 4;
    const int swr = (fr & 7) << 4;
    for (int jt = 0; jt < 8; ++jt) {
        // ---- mix + LN (all 512 threads) ----
        bf16x8 obv[8];
#pragma unroll
        for (int e = 0; e < 8; ++e) {
            float pv_[8];
#pragma unroll
            for (int h = 0; h < 8; ++h)
                pv_[h] = __expf(bf2f(sv[h][e]) - mh[h]) * ch[h];
            float cc[8];
#pragma unroll
            for (int gg = 0; gg < 8; ++gg) {
                float s = 0.f;
#pragma unroll
                for (int h = 0; h < 8; ++h) s += pv_[h] * Rc[h * 8 + gg];
                cc[gg] = s;  // already mean-centered over gg
            }
            float var = 0.f;
#pragma unroll
            for (int gg = 0; gg < 8; ++gg) var += cc[gg] * cc[gg];
            var *= 0.125f;
            float rs_ = rsqrtf(var + 1e-5f);
#pragma unroll
            for (int gg = 0; gg < 8; ++gg)
                obv[gg][e] = f2bf(cc[gg] * rs_ * rgs[gg] + rbs[gg]);
        }
#pragma unroll
        for (int gg = 0; gg < 8; ++gg)
            *(bf16x8*)((char*)A_lds + gg * 8192 + ti * 512 + ((jp * 16) ^ swm)) = obv[gg];
        // prefetch next S tile (hides HBM latency under PV)
        if (jt < 7) {
#pragma unroll
            for (int h = 0; h < 8; ++h)
                sv[h] = *(const bf16x8*)(S + sbase + (jt + 1) * 256 + h * hs);
        }
        __syncthreads();
        // ---- PV for this wave's head g ----
        const short* vb = Vt + (size_t)(b * 8 + g) * 64 * 2048 + jt * 256;
#pragma unroll
        for (int kk = 0; kk < 8; ++kk) {
            bf16x8 a = *(const bf16x8*)((char*)A_lds + g * 8192 + fr * 512 +
                                        (((kk * 32 + fq * 8) * 2) ^ swr));
#pragma unroll
            for (int n = 0; n < 4; ++n) {
                bf16x8 bv = *(const bf16x8*)(vb + (size_t)(n * 16 + fr) * 2048 + kk * 32 + fq * 8);
                acc[n] = __builtin_amdgcn_mfma_f32_16x16x32_bf16(a, bv, acc[n], 0, 0, 0);
            }
        }
        __syncthreads();
    }
#pragma unroll
    for (int n = 0; n < 4; ++n)
#pragma unroll
        for (int r = 0; r < 4; ++r)
            outh[((size_t)b * Nn + i0 + il0 + fq * 4 + r) * 512 + g * 64 + n * 16 + fr] =
                f2bf(acc[n][r]);
}

extern "C" void kernel_launch(void* const* d_in, const int* in_sizes, int n_in,
                              void* d_out, int out_size, void* d_ws, size_t ws_size,
                              hipStream_t stream) {
    const float* x      = (const float*)d_in[0];
    const float* ln_g   = (const float*)d_in[1];
    const float* ln_b   = (const float*)d_in[2];
    const float* w_qkv  = (const float*)d_in[3];
    const float* reattn = (const float*)d_in[4];
    const float* rn_g   = (const float*)d_in[5];
    const float* rn_b   = (const float*)d_in[6];
    const float* w_out  = (const float*)d_in[7];
    const float* b_out  = (const float*)d_in[8];
    float* out = (float*)d_out;

    char* ws = (char*)d_ws;
    short* wqkvT = (short*)ws; ws += (size_t)1536 * 512 * 2;
    short* woutT = (short*)ws; ws += (size_t)512 * 512 * 2;
    short* xn    = (short*)ws; ws += (size_t)8192 * 512 * 2;   // dead after k_qkv
    short* Q     = (short*)ws; ws += (size_t)32 * 2048 * 64 * 2;
    short* Kb    = (short*)ws; ws += (size_t)32 * 2048 * 64 * 2;
    short* Vt    = (short*)ws; ws += (size_t)32 * 64 * 2048 * 2;
    short* outh  = (short*)ws; ws += (size_t)8192 * 512 * 2;
    size_t fixed_bytes = (size_t)(ws - (char*)d_ws);
    short* attnC = (short*)ws;
    // stats alias the dead xn region (max 32*2048*4*2 = 1 MB << 8.39 MB)
    float* mstat = (float*)xn;
    float* lstat = mstat + (size_t)32 * 2048;

    int ICH = 2048;
    while (ICH > 64 && fixed_bytes + (size_t)32 * ICH * Nn * 2 > ws_size) ICH >>= 1;

    k_transpose_cast<<<(512 * 1536 + 255) / 256, 256, 0, stream>>>(w_qkv, wqkvT, 512, 1536);
    k_transpose_cast<<<(512 * 512 + 255) / 256, 256, 0, stream>>>(w_out, woutT, 512, 512);
    k_ln<<<8192 / 4, 256, 0, stream>>>(x, ln_g, ln_b, xn);
    k_qkv<<<dim3(8192 / 128, 1536 / 128), 256, 0, stream>>>(xn, wqkvT, Q, Kb, Vt);

    for (int i0 = 0; i0 < Nn; i0 += ICH) {
        k_scores_stats<<<dim3(ICH / 32, 32), 256, 0, stream>>>(Q, Kb, attnC, mstat, lstat, i0, ICH);
        k_mixpv<<<dim3(ICH / 16, 4), 512, 0, stream>>>(attnC, Vt, mstat, lstat,
                                                       reattn, rn_g, rn_b, outh, i0, ICH);
    }

    k_out<<<dim3(8192 / 128, 512 / 128), 256, 0, stream>>>(outh, woutT, b_out, out);
}

// Round 6
// 462.722 us; speedup vs baseline: 1.2314x; 1.1201x over previous
//
#include <hip/hip_runtime.h>
#include <hip/hip_bf16.h>
#include <math.h>

#define DEV __device__ __forceinline__

typedef short bf16x8 __attribute__((ext_vector_type(8)));
typedef short bf16x4 __attribute__((ext_vector_type(4)));
typedef float f32x4 __attribute__((ext_vector_type(4)));

static const int Nn = 2048;
static const int DIMd = 512;

DEV float bf2f(short u) {
    union { unsigned int i; float f; } c;
    c.i = ((unsigned int)(unsigned short)u) << 16;
    return c.f;
}

DEV short f2bf(float f) {
    union { float f; unsigned int i; } c;
    c.f = f;
    unsigned int u = c.i;
    unsigned int r = (u + 0x7fffu + ((u >> 16) & 1u)) >> 16;
    return (short)r;
}

// async global->LDS, 16B per lane (lane-linear LDS dest required)
DEV void gload16(const short* __restrict__ g, short* l) {
    __builtin_amdgcn_global_load_lds(
        (__attribute__((address_space(1))) void*)g,
        (__attribute__((address_space(3))) void*)l, 16, 0, 0);
}

// ---------------------------------------------------------------------------
// K0: transpose + cast f32 [K][N] -> bf16 [N][K]
// ---------------------------------------------------------------------------
__global__ void k_transpose_cast(const float* __restrict__ src,
                                 short* __restrict__ dst, int K, int N) {
    int o = blockIdx.x * 256 + threadIdx.x;
    if (o >= K * N) return;
    int n = o / K, k = o - n * K;
    dst[o] = f2bf(src[(size_t)k * N + n]);
}

// ---------------------------------------------------------------------------
// K1: row LayerNorm over DIM=512, f32 in -> bf16 out. One wave per row.
// ---------------------------------------------------------------------------
__global__ __launch_bounds__(256) void k_ln(const float* __restrict__ x,
                                            const float* __restrict__ g,
                                            const float* __restrict__ bta,
                                            short* __restrict__ xn) {
    int row = blockIdx.x * 4 + (threadIdx.x >> 6);
    int lane = threadIdx.x & 63;
    const float* xr = x + (size_t)row * DIMd;
    float4 v0 = ((const float4*)xr)[lane * 2];
    float4 v1 = ((const float4*)xr)[lane * 2 + 1];
    float f[8] = {v0.x, v0.y, v0.z, v0.w, v1.x, v1.y, v1.z, v1.w};
    float s = 0.f, sq = 0.f;
#pragma unroll
    for (int t = 0; t < 8; ++t) { s += f[t]; sq += f[t] * f[t]; }
#pragma unroll
    for (int off = 32; off >= 1; off >>= 1) {
        s += __shfl_xor(s, off);
        sq += __shfl_xor(sq, off);
    }
    float mu = s * (1.0f / 512.0f);
    float var = sq * (1.0f / 512.0f) - mu * mu;
    float rs = rsqrtf(var + 1e-5f);
    bf16x8 o;
#pragma unroll
    for (int t = 0; t < 8; ++t) {
        int c = lane * 8 + t;
        o[t] = f2bf((f[t] - mu) * rs * g[c] + bta[c]);
    }
    *(bf16x8*)(xn + (size_t)row * DIMd + lane * 8) = o;
}

// ---------------------------------------------------------------------------
// m97-style 128x128 tile GEMM main loop (A [M][K], B^T [N][K], k-contig).
// ---------------------------------------------------------------------------
DEV void gemm128_loop(const short* __restrict__ A, const short* __restrict__ B,
                      int K, int i0, int n0, int tid,
                      short* As, short* Bs, f32x4 acc[4][4]) {
    const int w = tid >> 6, wr = w >> 1, wc = w & 1;
    const int lane = tid & 63, fr = lane & 15, fq = lane >> 4;
    const int sr = tid >> 3, sc = (tid & 7) * 8;
    for (int k0 = 0; k0 < K; k0 += 64) {
#pragma unroll
        for (int L = 0; L < 4; ++L) {
            gload16(A + (size_t)(i0 + L * 32 + sr) * K + k0 + sc,
                    As + (L * 32 + sr) * 64 + sc);
            gload16(B + (size_t)(n0 + L * 32 + sr) * K + k0 + sc,
                    Bs + (L * 32 + sr) * 64 + sc);
        }
        __syncthreads();
#pragma unroll
        for (int kk = 0; kk < 2; ++kk) {
            bf16x8 af[4], bfr[4];
#pragma unroll
            for (int m = 0; m < 4; ++m)
                af[m] = *(const bf16x8*)(As + (wr * 64 + m * 16 + fr) * 64 + kk * 32 + fq * 8);
#pragma unroll
            for (int n = 0; n < 4; ++n)
                bfr[n] = *(const bf16x8*)(Bs + (wc * 64 + n * 16 + fr) * 64 + kk * 32 + fq * 8);
#pragma unroll
            for (int m = 0; m < 4; ++m)
#pragma unroll
                for (int n = 0; n < 4; ++n)
                    acc[m][n] = __builtin_amdgcn_mfma_f32_16x16x32_bf16(af[m], bfr[n], acc[m][n], 0, 0, 0);
        }
        __syncthreads();
    }
}

// ---------------------------------------------------------------------------
// K2: qkv = xn @ w_qkvT^T. Scatter epilogue into Q, K (k-contig) and Vt.
// ---------------------------------------------------------------------------
__global__ __launch_bounds__(256) void k_qkv(const short* __restrict__ xn,
                                             const short* __restrict__ wT,
                                             short* __restrict__ Q,
                                             short* __restrict__ Kb,
                                             short* __restrict__ Vt) {
    __shared__ short As[128 * 64], Bs[128 * 64];
    int tid = threadIdx.x;
    int i0 = blockIdx.x * 128, n0 = blockIdx.y * 128;
    f32x4 acc[4][4] = {};
    gemm128_loop(xn, wT, DIMd, i0, n0, tid, As, Bs, acc);
    const int w = tid >> 6, wr = w >> 1, wc = w & 1;
    const int lane = tid & 63, fr = lane & 15, fq = lane >> 4;
#pragma unroll
    for (int m = 0; m < 4; ++m) {
#pragma unroll
        for (int n = 0; n < 4; ++n) {
#pragma unroll
            for (int r = 0; r < 4; ++r) {
                int row = i0 + wr * 64 + m * 16 + fq * 4 + r;
                int c = n0 + wc * 64 + n * 16 + fr;
                short hv = f2bf(acc[m][n][r]);
                int b = row >> 11, i = row & 2047;
                int t = c >> 9, rem = c & 511;
                int h = rem >> 6, dd = rem & 63;
                size_t bh = (size_t)(b * 8 + h);
                if (t == 0)      Q [(bh * Nn + i) * 64 + dd] = hv;
                else if (t == 1) Kb[(bh * Nn + i) * 64 + dd] = hv;
                else             Vt[(bh * 64 + dd) * Nn + i] = hv;
            }
        }
    }
}

// ---------------------------------------------------------------------------
// K6: final = out_h @ w_outT^T + b_out. f32 out.
// ---------------------------------------------------------------------------
__global__ __launch_bounds__(256) void k_out(const short* __restrict__ outh,
                                             const short* __restrict__ wT,
                                             const float* __restrict__ bias,
                                             float* __restrict__ out) {
    __shared__ short As[128 * 64], Bs[128 * 64];
    int tid = threadIdx.x;
    int i0 = blockIdx.x * 128, n0 = blockIdx.y * 128;
    f32x4 acc[4][4] = {};
    gemm128_loop(outh, wT, 512, i0, n0, tid, As, Bs, acc);
    const int w = tid >> 6, wr = w >> 1, wc = w & 1;
    const int lane = tid & 63, fr = lane & 15, fq = lane >> 4;
#pragma unroll
    for (int m = 0; m < 4; ++m)
#pragma unroll
        for (int n = 0; n < 4; ++n)
#pragma unroll
            for (int r = 0; r < 4; ++r) {
                int row = i0 + wr * 64 + m * 16 + fq * 4 + r;
                int c = n0 + wc * 64 + n * 16 + fr;
                out[(size_t)row * 512 + c] = acc[m][n][r] + bias[c];
            }
}

// ---------------------------------------------------------------------------
// K3: scores + exact per-row softmax stats. Block = (bh, 32 i-rows), 4 waves
// stripe the j axis. Writes raw bf16 S once and (m, 1/l) f32 stats per row.
// ---------------------------------------------------------------------------
__global__ __launch_bounds__(256) void k_scores_stats(
    const short* __restrict__ Q, const short* __restrict__ Kb,
    short* __restrict__ S, float* __restrict__ mstat, float* __restrict__ lstat,
    int i0, int ICH) {
    int it = blockIdx.x, bh = blockIdx.y;
    int tid = threadIdx.x, w = tid >> 6, lane = tid & 63;
    int fr = lane & 15, fq = lane >> 4;
    int il0 = it * 32;
    const short* qb = Q + ((size_t)bh * Nn + i0 + il0) * 64;
    bf16x8 af[2][2];
#pragma unroll
    for (int m = 0; m < 2; ++m)
#pragma unroll
        for (int kk = 0; kk < 2; ++kk)
            af[m][kk] = *(const bf16x8*)(qb + (m * 16 + fr) * 64 + kk * 32 + fq * 8);
    float rm[2][4], rl[2][4];
#pragma unroll
    for (int m = 0; m < 2; ++m)
#pragma unroll
        for (int r = 0; r < 4; ++r) { rm[m][r] = -1e30f; rl[m][r] = 0.f; }
    __shared__ float wm[4][32], wl[4][32];
    for (int jt = 0; jt < 16; ++jt) {
        int j0 = jt * 128 + w * 32;
        const short* kb = Kb + ((size_t)bh * Nn + j0) * 64;
        f32x4 acc[2][2] = {};
#pragma unroll
        for (int kk = 0; kk < 2; ++kk) {
            bf16x8 bf0 = *(const bf16x8*)(kb + fr * 64 + kk * 32 + fq * 8);
            bf16x8 bf1 = *(const bf16x8*)(kb + (16 + fr) * 64 + kk * 32 + fq * 8);
#pragma unroll
            for (int m = 0; m < 2; ++m) {
                acc[m][0] = __builtin_amdgcn_mfma_f32_16x16x32_bf16(af[m][kk], bf0, acc[m][0], 0, 0, 0);
                acc[m][1] = __builtin_amdgcn_mfma_f32_16x16x32_bf16(af[m][kk], bf1, acc[m][1], 0, 0, 0);
            }
        }
#pragma unroll
        for (int m = 0; m < 2; ++m) {
            int ilr = il0 + m * 16 + fq * 4;
#pragma unroll
            for (int r = 0; r < 4; ++r) {
                short h0 = f2bf(acc[m][0][r] * 0.125f);
                short h1 = f2bf(acc[m][1][r] * 0.125f);
                size_t ro = ((size_t)bh * ICH + ilr + r) * 2048 + j0;
                S[ro + fr] = h0;
                S[ro + 16 + fr] = h1;
                float s0 = bf2f(h0), s1 = bf2f(h1);
                float v = fmaxf(s0, s1);
#pragma unroll
                for (int off = 8; off >= 1; off >>= 1) v = fmaxf(v, __shfl_xor(v, off));
                float te = __expf(s0 - v) + __expf(s1 - v);
#pragma unroll
                for (int off = 8; off >= 1; off >>= 1) te += __shfl_xor(te, off);
                float mn = fmaxf(rm[m][r], v);
                rl[m][r] = rl[m][r] * __expf(rm[m][r] - mn) + te * __expf(v - mn);
                rm[m][r] = mn;
            }
        }
    }
    if (fr == 0) {
#pragma unroll
        for (int m = 0; m < 2; ++m)
#pragma unroll
            for (int r = 0; r < 4; ++r) {
                wm[w][m * 16 + fq * 4 + r] = rm[m][r];
                wl[w][m * 16 + fq * 4 + r] = rl[m][r];
            }
    }
    __syncthreads();
    if (tid < 32) {
        float M = fmaxf(fmaxf(wm[0][tid], wm[1][tid]), fmaxf(wm[2][tid], wm[3][tid]));
        float L = wl[0][tid] * __expf(wm[0][tid] - M) + wl[1][tid] * __expf(wm[1][tid] - M)
                + wl[2][tid] * __expf(wm[2][tid] - M) + wl[3][tid] * __expf(wm[3][tid] - M);
        mstat[(size_t)bh * ICH + il0 + tid] = M;
        lstat[(size_t)bh * ICH + il0 + tid] = 1.0f / L;
    }
}

// ---------------------------------------------------------------------------
// K4: fused softmax-apply + head-mix + head-LN + PV. Block = (b, 16 i-rows),
// 8 waves. waves_per_eu(2,2) pins 1 block/CU and frees the allocator to use
// up to 256 VGPRs (round-5 lesson: launch_bounds min alone leaves cap at 128
// and spills ~150 MB scratch). Mix emits bf16x4 halves to cut peak liveness;
// softmax 1/l folded into exponent (zh = m + log l).
// ---------------------------------------------------------------------------
__global__ __launch_bounds__(512)
__attribute__((amdgpu_waves_per_eu(2, 2)))
void k_mixpv(
    const short* __restrict__ S, const short* __restrict__ Vt,
    const float* __restrict__ mstat, const float* __restrict__ lstat,
    const float* __restrict__ R, const float* __restrict__ rg,
    const float* __restrict__ rb,
    short* __restrict__ outh, int i0, int ICH) {
    __shared__ short A_lds[8 * 16 * 256];  // 64 KB, XOR-swizzled rows
    __shared__ float Rraw[64], Rc[64], rgs[8], rbs[8];
    int it = blockIdx.x, b = blockIdx.y;
    int il0 = it * 16;
    int tid = threadIdx.x;
    if (tid < 64) Rraw[tid] = R[tid];
    if (tid < 8) { rgs[tid] = rg[tid]; rbs[tid] = rb[tid]; }
    __syncthreads();
    if (tid < 64) {
        int h = tid >> 3;
        float mn = 0.f;
#pragma unroll
        for (int gg = 0; gg < 8; ++gg) mn += Rraw[h * 8 + gg];
        Rc[tid] = Rraw[tid] - mn * 0.125f;  // centered over g
    }
    int g = tid >> 6, lane = tid & 63, fr = lane & 15, fq = lane >> 4;
    int ti = tid >> 5, jp = tid & 31;
    // zh = m + log(l)  (so p = exp(s - zh) = exp(s - m) / l)
    float zh[8];
#pragma unroll
    for (int h = 0; h < 8; ++h) {
        size_t si = (size_t)(b * 8 + h) * ICH + il0 + ti;
        zh[h] = mstat[si] - __logf(lstat[si]);
    }
    const size_t hs = (size_t)ICH * 2048;
    size_t sbase = ((size_t)(b * 8) * ICH + il0 + ti) * 2048 + jp * 8;
    bf16x8 sv[8];
#pragma unroll
    for (int h = 0; h < 8; ++h) sv[h] = *(const bf16x8*)(S + sbase + h * hs);
    f32x4 acc[4] = {};
    __syncthreads();
    const int swm = (ti & 7) << 4;
    const int swr = (fr & 7) << 4;
    for (int jt = 0; jt < 8; ++jt) {
        // ---- mix + LN (all 512 threads), two bf16x4 halves ----
#pragma unroll
        for (int half = 0; half < 2; ++half) {
            bf16x4 ob[8];
#pragma unroll
            for (int e4 = 0; e4 < 4; ++e4) {
                const int e = half * 4 + e4;
                float pv_[8];
#pragma unroll
                for (int h = 0; h < 8; ++h)
                    pv_[h] = __expf(bf2f(sv[h][e]) - zh[h]);
                float cc[8];
#pragma unroll
                for (int gg = 0; gg < 8; ++gg) {
                    float s = 0.f;
#pragma unroll
                    for (int h = 0; h < 8; ++h) s += pv_[h] * Rc[h * 8 + gg];
                    cc[gg] = s;  // mean-centered over gg by construction
                }
                float var = 0.f;
#pragma unroll
                for (int gg = 0; gg < 8; ++gg) var += cc[gg] * cc[gg];
                var *= 0.125f;
                float rs_ = rsqrtf(var + 1e-5f);
#pragma unroll
                for (int gg = 0; gg < 8; ++gg)
                    ob[gg][e4] = f2bf(cc[gg] * rs_ * rgs[gg] + rbs[gg]);
            }
#pragma unroll
            for (int gg = 0; gg < 8; ++gg)
                *(bf16x4*)((char*)A_lds + gg * 8192 + ti * 512 +
                           ((jp * 16) ^ swm) + half * 8) = ob[gg];
        }
        // prefetch next S tile (hides HBM latency under PV)
        if (jt < 7) {
#pragma unroll
            for (int h = 0; h < 8; ++h)
                sv[h] = *(const bf16x8*)(S + sbase + (jt + 1) * 256 + h * hs);
        }
        __syncthreads();
        // ---- PV for this wave's head g ----
        const short* vb = Vt + (size_t)(b * 8 + g) * 64 * 2048 + jt * 256;
#pragma unroll
        for (int kk = 0; kk < 8; ++kk) {
            bf16x8 a = *(const bf16x8*)((char*)A_lds + g * 8192 + fr * 512 +
                                        (((kk * 32 + fq * 8) * 2) ^ swr));
#pragma unroll
            for (int n = 0; n < 4; ++n) {
                bf16x8 bv = *(const bf16x8*)(vb + (size_t)(n * 16 + fr) * 2048 + kk * 32 + fq * 8);
                acc[n] = __builtin_amdgcn_mfma_f32_16x16x32_bf16(a, bv, acc[n], 0, 0, 0);
            }
        }
        __syncthreads();
    }
#pragma unroll
    for (int n = 0; n < 4; ++n)
#pragma unroll
        for (int r = 0; r < 4; ++r)
            outh[((size_t)b * Nn + i0 + il0 + fq * 4 + r) * 512 + g * 64 + n * 16 + fr] =
                f2bf(acc[n][r]);
}

extern "C" void kernel_launch(void* const* d_in, const int* in_sizes, int n_in,
                              void* d_out, int out_size, void* d_ws, size_t ws_size,
                              hipStream_t stream) {
    const float* x      = (const float*)d_in[0];
    const float* ln_g   = (const float*)d_in[1];
    const float* ln_b   = (const float*)d_in[2];
    const float* w_qkv  = (const float*)d_in[3];
    const float* reattn = (const float*)d_in[4];
    const float* rn_g   = (const float*)d_in[5];
    const float* rn_b   = (const float*)d_in[6];
    const float* w_out  = (const float*)d_in[7];
    const float* b_out  = (const float*)d_in[8];
    float* out = (float*)d_out;

    char* ws = (char*)d_ws;
    short* wqkvT = (short*)ws; ws += (size_t)1536 * 512 * 2;
    short* woutT = (short*)ws; ws += (size_t)512 * 512 * 2;
    short* xn    = (short*)ws; ws += (size_t)8192 * 512 * 2;   // dead after k_qkv
    short* Q     = (short*)ws; ws += (size_t)32 * 2048 * 64 * 2;
    short* Kb    = (short*)ws; ws += (size_t)32 * 2048 * 64 * 2;
    short* Vt    = (short*)ws; ws += (size_t)32 * 64 * 2048 * 2;
    short* outh  = (short*)ws; ws += (size_t)8192 * 512 * 2;
    size_t fixed_bytes = (size_t)(ws - (char*)d_ws);
    short* attnC = (short*)ws;
    // stats alias the dead xn region (max 32*2048*4*2 = 1 MB << 8.39 MB)
    float* mstat = (float*)xn;
    float* lstat = mstat + (size_t)32 * 2048;

    int ICH = 2048;
    while (ICH > 64 && fixed_bytes + (size_t)32 * ICH * Nn * 2 > ws_size) ICH >>= 1;

    k_transpose_cast<<<(512 * 1536 + 255) / 256, 256, 0, stream>>>(w_qkv, wqkvT, 512, 1536);
    k_transpose_cast<<<(512 * 512 + 255) / 256, 256, 0, stream>>>(w_out, woutT, 512, 512);
    k_ln<<<8192 / 4, 256, 0, stream>>>(x, ln_g, ln_b, xn);
    k_qkv<<<dim3(8192 / 128, 1536 / 128), 256, 0, stream>>>(xn, wqkvT, Q, Kb, Vt);

    for (int i0 = 0; i0 < Nn; i0 += ICH) {
        k_scores_stats<<<dim3(ICH / 32, 32), 256, 0, stream>>>(Q, Kb, attnC, mstat, lstat, i0, ICH);
        k_mixpv<<<dim3(ICH / 16, 4), 512, 0, stream>>>(attnC, Vt, mstat, lstat,
                                                       reattn, rn_g, rn_b, outh, i0, ICH);
    }

    k_out<<<dim3(8192 / 128, 512 / 128), 256, 0, stream>>>(outh, woutT, b_out, out);
}

// Round 8
// 352.770 us; speedup vs baseline: 1.6153x; 1.3117x over previous
//
#include <hip/hip_runtime.h>
#include <hip/hip_bf16.h>
#include <math.h>

#define DEV __device__ __forceinline__

typedef short bf16x8 __attribute__((ext_vector_type(8)));
typedef short bf16x4 __attribute__((ext_vector_type(4)));
typedef float f32x4 __attribute__((ext_vector_type(4)));

static const int Nn = 2048;
static const int DIMd = 512;

DEV float bf2f(short u) {
    union { unsigned int i; float f; } c;
    c.i = ((unsigned int)(unsigned short)u) << 16;
    return c.f;
}

DEV short f2bf(float f) {
    union { float f; unsigned int i; } c;
    c.f = f;
    unsigned int u = c.i;
    unsigned int r = (u + 0x7fffu + ((u >> 16) & 1u)) >> 16;
    return (short)r;
}

// async global->LDS, 16B per lane (lane-linear LDS dest required)
DEV void gload16(const short* __restrict__ g, short* l) {
    __builtin_amdgcn_global_load_lds(
        (__attribute__((address_space(1))) void*)g,
        (__attribute__((address_space(3))) void*)l, 16, 0, 0);
}

// ---------------------------------------------------------------------------
// K0: transpose + cast f32 [K][N] -> bf16 [N][K]
// ---------------------------------------------------------------------------
__global__ void k_transpose_cast(const float* __restrict__ src,
                                 short* __restrict__ dst, int K, int N) {
    int o = blockIdx.x * 256 + threadIdx.x;
    if (o >= K * N) return;
    int n = o / K, k = o - n * K;
    dst[o] = f2bf(src[(size_t)k * N + n]);
}

// ---------------------------------------------------------------------------
// K1: row LayerNorm over DIM=512, f32 in -> bf16 out. One wave per row.
// ---------------------------------------------------------------------------
__global__ __launch_bounds__(256) void k_ln(const float* __restrict__ x,
                                            const float* __restrict__ g,
                                            const float* __restrict__ bta,
                                            short* __restrict__ xn) {
    int row = blockIdx.x * 4 + (threadIdx.x >> 6);
    int lane = threadIdx.x & 63;
    const float* xr = x + (size_t)row * DIMd;
    float4 v0 = ((const float4*)xr)[lane * 2];
    float4 v1 = ((const float4*)xr)[lane * 2 + 1];
    float f[8] = {v0.x, v0.y, v0.z, v0.w, v1.x, v1.y, v1.z, v1.w};
    float s = 0.f, sq = 0.f;
#pragma unroll
    for (int t = 0; t < 8; ++t) { s += f[t]; sq += f[t] * f[t]; }
#pragma unroll
    for (int off = 32; off >= 1; off >>= 1) {
        s += __shfl_xor(s, off);
        sq += __shfl_xor(sq, off);
    }
    float mu = s * (1.0f / 512.0f);
    float var = sq * (1.0f / 512.0f) - mu * mu;
    float rs = rsqrtf(var + 1e-5f);
    bf16x8 o;
#pragma unroll
    for (int t = 0; t < 8; ++t) {
        int c = lane * 8 + t;
        o[t] = f2bf((f[t] - mu) * rs * g[c] + bta[c]);
    }
    *(bf16x8*)(xn + (size_t)row * DIMd + lane * 8) = o;
}

// ---------------------------------------------------------------------------
// m97-style 128x128 tile GEMM main loop (A [M][K], B^T [N][K], k-contig).
// ---------------------------------------------------------------------------
DEV void gemm128_loop(const short* __restrict__ A, const short* __restrict__ B,
                      int K, int i0, int n0, int tid,
                      short* As, short* Bs, f32x4 acc[4][4]) {
    const int w = tid >> 6, wr = w >> 1, wc = w & 1;
    const int lane = tid & 63, fr = lane & 15, fq = lane >> 4;
    const int sr = tid >> 3, sc = (tid & 7) * 8;
    for (int k0 = 0; k0 < K; k0 += 64) {
#pragma unroll
        for (int L = 0; L < 4; ++L) {
            gload16(A + (size_t)(i0 + L * 32 + sr) * K + k0 + sc,
                    As + (L * 32 + sr) * 64 + sc);
            gload16(B + (size_t)(n0 + L * 32 + sr) * K + k0 + sc,
                    Bs + (L * 32 + sr) * 64 + sc);
        }
        __syncthreads();
#pragma unroll
        for (int kk = 0; kk < 2; ++kk) {
            bf16x8 af[4], bfr[4];
#pragma unroll
            for (int m = 0; m < 4; ++m)
                af[m] = *(const bf16x8*)(As + (wr * 64 + m * 16 + fr) * 64 + kk * 32 + fq * 8);
#pragma unroll
            for (int n = 0; n < 4; ++n)
                bfr[n] = *(const bf16x8*)(Bs + (wc * 64 + n * 16 + fr) * 64 + kk * 32 + fq * 8);
#pragma unroll
            for (int m = 0; m < 4; ++m)
#pragma unroll
                for (int n = 0; n < 4; ++n)
                    acc[m][n] = __builtin_amdgcn_mfma_f32_16x16x32_bf16(af[m], bfr[n], acc[m][n], 0, 0, 0);
        }
        __syncthreads();
    }
}

// ---------------------------------------------------------------------------
// K2: qkv = xn @ w_qkvT^T. Scatter epilogue into Q, K (k-contig) and Vt.
// ---------------------------------------------------------------------------
__global__ __launch_bounds__(256) void k_qkv(const short* __restrict__ xn,
                                             const short* __restrict__ wT,
                                             short* __restrict__ Q,
                                             short* __restrict__ Kb,
                                             short* __restrict__ Vt) {
    __shared__ short As[128 * 64], Bs[128 * 64];
    int tid = threadIdx.x;
    int i0 = blockIdx.x * 128, n0 = blockIdx.y * 128;
    f32x4 acc[4][4] = {};
    gemm128_loop(xn, wT, DIMd, i0, n0, tid, As, Bs, acc);
    const int w = tid >> 6, wr = w >> 1, wc = w & 1;
    const int lane = tid & 63, fr = lane & 15, fq = lane >> 4;
#pragma unroll
    for (int m = 0; m < 4; ++m) {
#pragma unroll
        for (int n = 0; n < 4; ++n) {
#pragma unroll
            for (int r = 0; r < 4; ++r) {
                int row = i0 + wr * 64 + m * 16 + fq * 4 + r;
                int c = n0 + wc * 64 + n * 16 + fr;
                short hv = f2bf(acc[m][n][r]);
                int b = row >> 11, i = row & 2047;
                int t = c >> 9, rem = c & 511;
                int h = rem >> 6, dd = rem & 63;
                size_t bh = (size_t)(b * 8 + h);
                if (t == 0)      Q [(bh * Nn + i) * 64 + dd] = hv;
                else if (t == 1) Kb[(bh * Nn + i) * 64 + dd] = hv;
                else             Vt[(bh * 64 + dd) * Nn + i] = hv;
            }
        }
    }
}

// ---------------------------------------------------------------------------
// K6: final = out_h @ w_outT^T + b_out. f32 out.
// ---------------------------------------------------------------------------
__global__ __launch_bounds__(256) void k_out(const short* __restrict__ outh,
                                             const short* __restrict__ wT,
                                             const float* __restrict__ bias,
                                             float* __restrict__ out) {
    __shared__ short As[128 * 64], Bs[128 * 64];
    int tid = threadIdx.x;
    int i0 = blockIdx.x * 128, n0 = blockIdx.y * 128;
    f32x4 acc[4][4] = {};
    gemm128_loop(outh, wT, 512, i0, n0, tid, As, Bs, acc);
    const int w = tid >> 6, wr = w >> 1, wc = w & 1;
    const int lane = tid & 63, fr = lane & 15, fq = lane >> 4;
#pragma unroll
    for (int m = 0; m < 4; ++m)
#pragma unroll
        for (int n = 0; n < 4; ++n)
#pragma unroll
            for (int r = 0; r < 4; ++r) {
                int row = i0 + wr * 64 + m * 16 + fq * 4 + r;
                int c = n0 + wc * 64 + n * 16 + fr;
                out[(size_t)row * 512 + c] = acc[m][n][r] + bias[c];
            }
}

// XCD-aware decode of a 256-block 1-D grid into (b, i0). Each XCD pair-half
// works one batch's K/V panel (4 MB -> fits one XCD L2).
DEV void decode_bid(int bid, int& b, int& i0) {
    int xcd = bid & 7, slot = bid >> 3;
    b = xcd >> 1;
    i0 = ((xcd & 1) * 32 + slot) * 32;
}

// ---------------------------------------------------------------------------
// K3: stats pass. Block = 8 waves; wave h owns head h, 32 q-rows. Swapped
// QK^T (mfma(K,Q): D[row=j][col=i]). Online per-i (m, l) over all 2048 j.
// Writes zh = m*scale + log(l). MFMA sequence identical to k_fused phase A.
// ---------------------------------------------------------------------------
__global__ __launch_bounds__(512) void k_stats(const short* __restrict__ Q,
                                               const short* __restrict__ Kb,
                                               float* __restrict__ zstat) {
    int b, i0;
    decode_bid(blockIdx.x, b, i0);
    int tid = threadIdx.x, wv = tid >> 6, lane = tid & 63;
    int fr = lane & 15, fq = lane >> 4;
    size_t bh = (size_t)(b * 8 + wv);
    const short* qb = Q + (bh * Nn + i0) * 64;
    bf16x8 qf[2][2];
#pragma unroll
    for (int in = 0; in < 2; ++in)
#pragma unroll
        for (int kk = 0; kk < 2; ++kk)
            qf[in][kk] = *(const bf16x8*)(qb + (in * 16 + fr) * 64 + kk * 32 + fq * 8);
    float m[2] = {-1e30f, -1e30f}, l[2] = {0.f, 0.f};
    const short* kbase = Kb + bh * Nn * 64;
    for (int jt = 0; jt < 32; ++jt) {
        const short* kb = kbase + jt * 64 * 64;
        f32x4 acc[4][2] = {};
#pragma unroll
        for (int kk = 0; kk < 2; ++kk)
#pragma unroll
            for (int jm = 0; jm < 4; ++jm) {
                bf16x8 kf = *(const bf16x8*)(kb + (jm * 16 + fr) * 64 + kk * 32 + fq * 8);
                acc[jm][0] = __builtin_amdgcn_mfma_f32_16x16x32_bf16(kf, qf[0][kk], acc[jm][0], 0, 0, 0);
                acc[jm][1] = __builtin_amdgcn_mfma_f32_16x16x32_bf16(kf, qf[1][kk], acc[jm][1], 0, 0, 0);
            }
#pragma unroll
        for (int in = 0; in < 2; ++in) {
            float mt = acc[0][in][0];
#pragma unroll
            for (int jm = 0; jm < 4; ++jm)
#pragma unroll
                for (int r = 0; r < 4; ++r) mt = fmaxf(mt, acc[jm][in][r]);
            mt = fmaxf(mt, __shfl_xor(mt, 16));
            mt = fmaxf(mt, __shfl_xor(mt, 32));
            float es = 0.f;
#pragma unroll
            for (int jm = 0; jm < 4; ++jm)
#pragma unroll
                for (int r = 0; r < 4; ++r)
                    es += __expf((acc[jm][in][r] - mt) * 0.125f);
            es += __shfl_xor(es, 16);
            es += __shfl_xor(es, 32);
            float mn = fmaxf(m[in], mt);
            l[in] = l[in] * __expf((m[in] - mn) * 0.125f) + es * __expf((mt - mn) * 0.125f);
            m[in] = mn;
        }
    }
    if (fq == 0) {
#pragma unroll
        for (int in = 0; in < 2; ++in)
            zstat[bh * Nn + i0 + in * 16 + fr] = m[in] * 0.125f + __logf(l[in]);
    }
}

// ---------------------------------------------------------------------------
// K4: fully fused pass. Per jt: recompute QK^T (swapped) -> p=exp(s-zh) ->
// S_lds (bf16, XOR-swizzled [h][32i][64j]) -> barrier -> cross-head mix +
// head-LN -> P_lds -> barrier -> PV MFMA accumulate. No S ever touches HBM.
// Phase-B mapping (round-7 bugfix): thread owns ONE bf16x4 quad —
// mi = tid>>4 (32 rows), j4 = (tid&15)*4 (16 quads = 64 j). 32x16=512 ✓.
// ---------------------------------------------------------------------------
__global__ __launch_bounds__(512)
__attribute__((amdgpu_waves_per_eu(2, 2)))
void k_fused(const short* __restrict__ Q, const short* __restrict__ Kb,
             const short* __restrict__ Vt, const float* __restrict__ zstat,
             const float* __restrict__ R, const float* __restrict__ rg,
             const float* __restrict__ rb, short* __restrict__ outh) {
    __shared__ short S_lds[8 * 32 * 64];  // [h][32i][64j] bf16, swz — 32 KB
    __shared__ short P_lds[8 * 32 * 64];  // [g][32i][64j] bf16, swz — 32 KB
    __shared__ float Rraw[64], Rc[64], rgs[8], rbs[8], zl[8 * 32];
    int b, i0;
    decode_bid(blockIdx.x, b, i0);
    int tid = threadIdx.x, wv = tid >> 6, lane = tid & 63;
    int fr = lane & 15, fq = lane >> 4;
    if (tid < 64) Rraw[tid] = R[tid];
    if (tid < 8) { rgs[tid] = rg[tid]; rbs[tid] = rb[tid]; }
    if (tid >= 64 && tid < 320) {
        int q = tid - 64;
        zl[q] = zstat[(size_t)(b * 8 + (q >> 5)) * Nn + i0 + (q & 31)];
    }
    __syncthreads();
    if (tid < 64) {
        int h = tid >> 3;
        float mn = 0.f;
#pragma unroll
        for (int gg = 0; gg < 8; ++gg) mn += Rraw[h * 8 + gg];
        Rc[tid] = Rraw[tid] - mn * 0.125f;  // row-centered mix matrix
    }
    size_t bh = (size_t)(b * 8 + wv);
    const short* qb = Q + (bh * Nn + i0) * 64;
    bf16x8 qf[2][2];
#pragma unroll
    for (int in = 0; in < 2; ++in)
#pragma unroll
        for (int kk = 0; kk < 2; ++kk)
            qf[in][kk] = *(const bf16x8*)(qb + (in * 16 + fr) * 64 + kk * 32 + fq * 8);
    float zh[2] = {zl[wv * 32 + fr], zl[wv * 32 + 16 + fr]};
    const short* kbase = Kb + bh * Nn * 64;
    const short* vbase = Vt + bh * 64 * Nn;
    const int mi = tid >> 4, j4 = (tid & 15) * 4;  // mix-phase ownership
    const int msw = (mi & 7) << 4;
    f32x4 acc_o[2][4] = {};
    for (int jt = 0; jt < 32; ++jt) {
        // ---- phase A: QK^T (swapped) + exp + S_lds write ----
        {
            const short* kb = kbase + jt * 64 * 64;
            f32x4 acc[4][2] = {};
#pragma unroll
            for (int kk = 0; kk < 2; ++kk)
#pragma unroll
                for (int jm = 0; jm < 4; ++jm) {
                    bf16x8 kf = *(const bf16x8*)(kb + (jm * 16 + fr) * 64 + kk * 32 + fq * 8);
                    acc[jm][0] = __builtin_amdgcn_mfma_f32_16x16x32_bf16(kf, qf[0][kk], acc[jm][0], 0, 0, 0);
                    acc[jm][1] = __builtin_amdgcn_mfma_f32_16x16x32_bf16(kf, qf[1][kk], acc[jm][1], 0, 0, 0);
                }
#pragma unroll
            for (int in = 0; in < 2; ++in) {
                int i = in * 16 + fr;
                int sw = (i & 7) << 4;
#pragma unroll
                for (int jm = 0; jm < 4; ++jm) {
                    bf16x4 pk;
#pragma unroll
                    for (int r = 0; r < 4; ++r)
                        pk[r] = f2bf(__expf(acc[jm][in][r] * 0.125f - zh[in]));
                    int j0 = jm * 16 + fq * 4;
                    *(bf16x4*)((char*)S_lds + wv * 4096 + i * 128 + ((j0 * 2) ^ sw)) = pk;
                }
            }
        }
        __syncthreads();
        // ---- phase B: cross-head mix + head-LN (one bf16x4 quad/thread) ----
        {
            bf16x4 sh[8];
#pragma unroll
            for (int h = 0; h < 8; ++h)
                sh[h] = *(const bf16x4*)((char*)S_lds + h * 4096 + mi * 128 + ((j4 * 2) ^ msw));
            bf16x4 og[8];
#pragma unroll
            for (int e = 0; e < 4; ++e) {
                float pv[8];
#pragma unroll
                for (int h = 0; h < 8; ++h) pv[h] = bf2f(sh[h][e]);
                float cc[8];
#pragma unroll
                for (int gg = 0; gg < 8; ++gg) {
                    float s = 0.f;
#pragma unroll
                    for (int h = 0; h < 8; ++h) s += pv[h] * Rc[h * 8 + gg];
                    cc[gg] = s;  // mean over gg is 0 by construction
                }
                float var = 0.f;
#pragma unroll
                for (int gg = 0; gg < 8; ++gg) var += cc[gg] * cc[gg];
                var *= 0.125f;
                float rs_ = rsqrtf(var + 1e-5f);
#pragma unroll
                for (int gg = 0; gg < 8; ++gg)
                    og[gg][e] = f2bf(cc[gg] * rs_ * rgs[gg] + rbs[gg]);
            }
#pragma unroll
            for (int gg = 0; gg < 8; ++gg)
                *(bf16x4*)((char*)P_lds + gg * 4096 + mi * 128 + ((j4 * 2) ^ msw)) = og[gg];
        }
        __syncthreads();
        // ---- phase C: PV for this wave's head g = wv ----
        {
            const short* vb = vbase + jt * 64;
#pragma unroll
            for (int kk = 0; kk < 2; ++kk) {
                bf16x8 vf[4];
#pragma unroll
                for (int dn = 0; dn < 4; ++dn)
                    vf[dn] = *(const bf16x8*)(vb + (size_t)(dn * 16 + fr) * Nn + kk * 32 + fq * 8);
#pragma unroll
                for (int im = 0; im < 2; ++im) {
                    int row = im * 16 + fr;
                    bf16x8 pa = *(const bf16x8*)((char*)P_lds + wv * 4096 + row * 128 +
                                                 (((kk * 32 + fq * 8) * 2) ^ ((row & 7) << 4)));
#pragma unroll
                    for (int dn = 0; dn < 4; ++dn)
                        acc_o[im][dn] = __builtin_amdgcn_mfma_f32_16x16x32_bf16(pa, vf[dn], acc_o[im][dn], 0, 0, 0);
                }
            }
        }
        __syncthreads();
    }
#pragma unroll
    for (int im = 0; im < 2; ++im)
#pragma unroll
        for (int dn = 0; dn < 4; ++dn)
#pragma unroll
            for (int r = 0; r < 4; ++r)
                outh[((size_t)b * Nn + i0 + im * 16 + fq * 4 + r) * 512 + wv * 64 + dn * 16 + fr] =
                    f2bf(acc_o[im][dn][r]);
}

extern "C" void kernel_launch(void* const* d_in, const int* in_sizes, int n_in,
                              void* d_out, int out_size, void* d_ws, size_t ws_size,
                              hipStream_t stream) {
    const float* x      = (const float*)d_in[0];
    const float* ln_g   = (const float*)d_in[1];
    const float* ln_b   = (const float*)d_in[2];
    const float* w_qkv  = (const float*)d_in[3];
    const float* reattn = (const float*)d_in[4];
    const float* rn_g   = (const float*)d_in[5];
    const float* rn_b   = (const float*)d_in[6];
    const float* w_out  = (const float*)d_in[7];
    const float* b_out  = (const float*)d_in[8];
    float* out = (float*)d_out;

    char* ws = (char*)d_ws;
    short* wqkvT = (short*)ws; ws += (size_t)1536 * 512 * 2;
    short* woutT = (short*)ws; ws += (size_t)512 * 512 * 2;
    short* xn    = (short*)ws; ws += (size_t)8192 * 512 * 2;   // dead after k_qkv
    short* Q     = (short*)ws; ws += (size_t)32 * 2048 * 64 * 2;
    short* Kb    = (short*)ws; ws += (size_t)32 * 2048 * 64 * 2;
    short* Vt    = (short*)ws; ws += (size_t)32 * 64 * 2048 * 2;
    short* outh  = (short*)ws; ws += (size_t)8192 * 512 * 2;
    // zh stats alias the dead xn region (32*2048*4 = 256 KB << 8.39 MB)
    float* zstat = (float*)xn;

    k_transpose_cast<<<(512 * 1536 + 255) / 256, 256, 0, stream>>>(w_qkv, wqkvT, 512, 1536);
    k_transpose_cast<<<(512 * 512 + 255) / 256, 256, 0, stream>>>(w_out, woutT, 512, 512);
    k_ln<<<8192 / 4, 256, 0, stream>>>(x, ln_g, ln_b, xn);
    k_qkv<<<dim3(8192 / 128, 1536 / 128), 256, 0, stream>>>(xn, wqkvT, Q, Kb, Vt);

    k_stats<<<256, 512, 0, stream>>>(Q, Kb, zstat);
    k_fused<<<256, 512, 0, stream>>>(Q, Kb, Vt, zstat, reattn, rn_g, rn_b, outh);

    k_out<<<dim3(8192 / 128, 512 / 128), 256, 0, stream>>>(outh, woutT, b_out, out);
}

// Round 9
// 341.899 us; speedup vs baseline: 1.6666x; 1.0318x over previous
//
#include <hip/hip_runtime.h>
#include <hip/hip_bf16.h>
#include <math.h>

#define DEV __device__ __forceinline__

typedef short bf16x8 __attribute__((ext_vector_type(8)));
typedef short bf16x4 __attribute__((ext_vector_type(4)));
typedef float f32x4 __attribute__((ext_vector_type(4)));

static const int Nn = 2048;
static const int DIMd = 512;

DEV float bf2f(short u) {
    union { unsigned int i; float f; } c;
    c.i = ((unsigned int)(unsigned short)u) << 16;
    return c.f;
}

DEV short f2bf(float f) {
    union { float f; unsigned int i; } c;
    c.f = f;
    unsigned int u = c.i;
    unsigned int r = (u + 0x7fffu + ((u >> 16) & 1u)) >> 16;
    return (short)r;
}

// async global->LDS, 16B per lane (lane-linear LDS dest required)
DEV void gload16(const short* __restrict__ g, short* l) {
    __builtin_amdgcn_global_load_lds(
        (__attribute__((address_space(1))) void*)g,
        (__attribute__((address_space(3))) void*)l, 16, 0, 0);
}

// ---------------------------------------------------------------------------
// K0: transpose + cast f32 [K][N] -> bf16 [N][K]
// ---------------------------------------------------------------------------
__global__ void k_transpose_cast(const float* __restrict__ src,
                                 short* __restrict__ dst, int K, int N) {
    int o = blockIdx.x * 256 + threadIdx.x;
    if (o >= K * N) return;
    int n = o / K, k = o - n * K;
    dst[o] = f2bf(src[(size_t)k * N + n]);
}

// ---------------------------------------------------------------------------
// K1: row LayerNorm over DIM=512, f32 in -> bf16 out. One wave per row.
// ---------------------------------------------------------------------------
__global__ __launch_bounds__(256) void k_ln(const float* __restrict__ x,
                                            const float* __restrict__ g,
                                            const float* __restrict__ bta,
                                            short* __restrict__ xn) {
    int row = blockIdx.x * 4 + (threadIdx.x >> 6);
    int lane = threadIdx.x & 63;
    const float* xr = x + (size_t)row * DIMd;
    float4 v0 = ((const float4*)xr)[lane * 2];
    float4 v1 = ((const float4*)xr)[lane * 2 + 1];
    float f[8] = {v0.x, v0.y, v0.z, v0.w, v1.x, v1.y, v1.z, v1.w};
    float s = 0.f, sq = 0.f;
#pragma unroll
    for (int t = 0; t < 8; ++t) { s += f[t]; sq += f[t] * f[t]; }
#pragma unroll
    for (int off = 32; off >= 1; off >>= 1) {
        s += __shfl_xor(s, off);
        sq += __shfl_xor(sq, off);
    }
    float mu = s * (1.0f / 512.0f);
    float var = sq * (1.0f / 512.0f) - mu * mu;
    float rs = rsqrtf(var + 1e-5f);
    bf16x8 o;
#pragma unroll
    for (int t = 0; t < 8; ++t) {
        int c = lane * 8 + t;
        o[t] = f2bf((f[t] - mu) * rs * g[c] + bta[c]);
    }
    *(bf16x8*)(xn + (size_t)row * DIMd + lane * 8) = o;
}

// ---------------------------------------------------------------------------
// m97-style 128x128 tile GEMM main loop (A [M][K], B^T [N][K], k-contig).
// ---------------------------------------------------------------------------
DEV void gemm128_loop(const short* __restrict__ A, const short* __restrict__ B,
                      int K, int i0, int n0, int tid,
                      short* As, short* Bs, f32x4 acc[4][4]) {
    const int w = tid >> 6, wr = w >> 1, wc = w & 1;
    const int lane = tid & 63, fr = lane & 15, fq = lane >> 4;
    const int sr = tid >> 3, sc = (tid & 7) * 8;
    for (int k0 = 0; k0 < K; k0 += 64) {
#pragma unroll
        for (int L = 0; L < 4; ++L) {
            gload16(A + (size_t)(i0 + L * 32 + sr) * K + k0 + sc,
                    As + (L * 32 + sr) * 64 + sc);
            gload16(B + (size_t)(n0 + L * 32 + sr) * K + k0 + sc,
                    Bs + (L * 32 + sr) * 64 + sc);
        }
        __syncthreads();
#pragma unroll
        for (int kk = 0; kk < 2; ++kk) {
            bf16x8 af[4], bfr[4];
#pragma unroll
            for (int m = 0; m < 4; ++m)
                af[m] = *(const bf16x8*)(As + (wr * 64 + m * 16 + fr) * 64 + kk * 32 + fq * 8);
#pragma unroll
            for (int n = 0; n < 4; ++n)
                bfr[n] = *(const bf16x8*)(Bs + (wc * 64 + n * 16 + fr) * 64 + kk * 32 + fq * 8);
#pragma unroll
            for (int m = 0; m < 4; ++m)
#pragma unroll
                for (int n = 0; n < 4; ++n)
                    acc[m][n] = __builtin_amdgcn_mfma_f32_16x16x32_bf16(af[m], bfr[n], acc[m][n], 0, 0, 0);
        }
        __syncthreads();
    }
}

// ---------------------------------------------------------------------------
// K2: qkv = xn @ w_qkvT^T. Scatter epilogue into Q, K (k-contig) and Vt.
// ---------------------------------------------------------------------------
__global__ __launch_bounds__(256) void k_qkv(const short* __restrict__ xn,
                                             const short* __restrict__ wT,
                                             short* __restrict__ Q,
                                             short* __restrict__ Kb,
                                             short* __restrict__ Vt) {
    __shared__ short As[128 * 64], Bs[128 * 64];
    int tid = threadIdx.x;
    int i0 = blockIdx.x * 128, n0 = blockIdx.y * 128;
    f32x4 acc[4][4] = {};
    gemm128_loop(xn, wT, DIMd, i0, n0, tid, As, Bs, acc);
    const int w = tid >> 6, wr = w >> 1, wc = w & 1;
    const int lane = tid & 63, fr = lane & 15, fq = lane >> 4;
#pragma unroll
    for (int m = 0; m < 4; ++m) {
#pragma unroll
        for (int n = 0; n < 4; ++n) {
#pragma unroll
            for (int r = 0; r < 4; ++r) {
                int row = i0 + wr * 64 + m * 16 + fq * 4 + r;
                int c = n0 + wc * 64 + n * 16 + fr;
                short hv = f2bf(acc[m][n][r]);
                int b = row >> 11, i = row & 2047;
                int t = c >> 9, rem = c & 511;
                int h = rem >> 6, dd = rem & 63;
                size_t bh = (size_t)(b * 8 + h);
                if (t == 0)      Q [(bh * Nn + i) * 64 + dd] = hv;
                else if (t == 1) Kb[(bh * Nn + i) * 64 + dd] = hv;
                else             Vt[(bh * 64 + dd) * Nn + i] = hv;
            }
        }
    }
}

// ---------------------------------------------------------------------------
// K6: final = out_h @ w_outT^T + b_out. f32 out.
// ---------------------------------------------------------------------------
__global__ __launch_bounds__(256) void k_out(const short* __restrict__ outh,
                                             const short* __restrict__ wT,
                                             const float* __restrict__ bias,
                                             float* __restrict__ out) {
    __shared__ short As[128 * 64], Bs[128 * 64];
    int tid = threadIdx.x;
    int i0 = blockIdx.x * 128, n0 = blockIdx.y * 128;
    f32x4 acc[4][4] = {};
    gemm128_loop(outh, wT, 512, i0, n0, tid, As, Bs, acc);
    const int w = tid >> 6, wr = w >> 1, wc = w & 1;
    const int lane = tid & 63, fr = lane & 15, fq = lane >> 4;
#pragma unroll
    for (int m = 0; m < 4; ++m)
#pragma unroll
        for (int n = 0; n < 4; ++n)
#pragma unroll
            for (int r = 0; r < 4; ++r) {
                int row = i0 + wr * 64 + m * 16 + fq * 4 + r;
                int c = n0 + wc * 64 + n * 16 + fr;
                out[(size_t)row * 512 + c] = acc[m][n][r] + bias[c];
            }
}

// XCD-aware decode of a 512-block 1-D grid into (b, i0, jh). Blocks sharing
// (b, jh) land on one XCD => that XCD's L2 holds one K/V half-panel (~2 MB).
DEV void decode_bid2(int bid, int& b, int& i0, int& jh) {
    int xcd = bid & 7, slot = bid >> 3;  // slot 0..63
    b = xcd >> 1;
    jh = xcd & 1;
    i0 = slot * 32;
}

// ---------------------------------------------------------------------------
// K3a: stats partials. Block = (b, i0, jh); wave h owns head h, 32 q-rows,
// 1024 j (16 jt). Swapped QK^T. Writes partial (m, l) per (bh, i).
// ---------------------------------------------------------------------------
__global__ __launch_bounds__(512, 4) void k_stats(const short* __restrict__ Q,
                                                  const short* __restrict__ Kb,
                                                  float* __restrict__ mpart,
                                                  float* __restrict__ lpart) {
    int b, i0, jh;
    decode_bid2(blockIdx.x, b, i0, jh);
    int tid = threadIdx.x, wv = tid >> 6, lane = tid & 63;
    int fr = lane & 15, fq = lane >> 4;
    size_t bh = (size_t)(b * 8 + wv);
    const short* qb = Q + (bh * Nn + i0) * 64;
    bf16x8 qf[2][2];
#pragma unroll
    for (int in = 0; in < 2; ++in)
#pragma unroll
        for (int kk = 0; kk < 2; ++kk)
            qf[in][kk] = *(const bf16x8*)(qb + (in * 16 + fr) * 64 + kk * 32 + fq * 8);
    float m[2] = {-1e30f, -1e30f}, l[2] = {0.f, 0.f};
    const short* kbase = Kb + bh * Nn * 64 + (size_t)jh * 1024 * 64;
    for (int jt = 0; jt < 16; ++jt) {
        const short* kb = kbase + jt * 64 * 64;
        f32x4 acc[4][2] = {};
#pragma unroll
        for (int kk = 0; kk < 2; ++kk)
#pragma unroll
            for (int jm = 0; jm < 4; ++jm) {
                bf16x8 kf = *(const bf16x8*)(kb + (jm * 16 + fr) * 64 + kk * 32 + fq * 8);
                acc[jm][0] = __builtin_amdgcn_mfma_f32_16x16x32_bf16(kf, qf[0][kk], acc[jm][0], 0, 0, 0);
                acc[jm][1] = __builtin_amdgcn_mfma_f32_16x16x32_bf16(kf, qf[1][kk], acc[jm][1], 0, 0, 0);
            }
#pragma unroll
        for (int in = 0; in < 2; ++in) {
            float mt = acc[0][in][0];
#pragma unroll
            for (int jm = 0; jm < 4; ++jm)
#pragma unroll
                for (int r = 0; r < 4; ++r) mt = fmaxf(mt, acc[jm][in][r]);
            mt = fmaxf(mt, __shfl_xor(mt, 16));
            mt = fmaxf(mt, __shfl_xor(mt, 32));
            float es = 0.f;
#pragma unroll
            for (int jm = 0; jm < 4; ++jm)
#pragma unroll
                for (int r = 0; r < 4; ++r)
                    es += __expf((acc[jm][in][r] - mt) * 0.125f);
            es += __shfl_xor(es, 16);
            es += __shfl_xor(es, 32);
            float mn = fmaxf(m[in], mt);
            l[in] = l[in] * __expf((m[in] - mn) * 0.125f) + es * __expf((mt - mn) * 0.125f);
            m[in] = mn;
        }
    }
    if (fq == 0) {
#pragma unroll
        for (int in = 0; in < 2; ++in) {
            size_t o = (size_t)jh * 65536 + bh * Nn + i0 + in * 16 + fr;
            mpart[o] = m[in];
            lpart[o] = l[in];
        }
    }
}

// ---------------------------------------------------------------------------
// K3b: combine the two j-half stats -> zh = m*scale + log(l). 65536 elems.
// ---------------------------------------------------------------------------
__global__ __launch_bounds__(256) void k_zcomb(const float* __restrict__ mpart,
                                               const float* __restrict__ lpart,
                                               float* __restrict__ zstat) {
    int idx = blockIdx.x * 256 + threadIdx.x;
    float m0 = mpart[idx], m1 = mpart[65536 + idx];
    float l0 = lpart[idx], l1 = lpart[65536 + idx];
    float M = fmaxf(m0, m1);
    float L = l0 * __expf((m0 - M) * 0.125f) + l1 * __expf((m1 - M) * 0.125f);
    zstat[idx] = M * 0.125f + __logf(L);
}

// ---------------------------------------------------------------------------
// K4: fully fused pass, split-j. Block = (b, 32 i-rows, jh); 16 jt.
// Per jt: recompute QK^T (swapped) -> p=exp(s-zh) -> S_lds (swz) -> barrier
// -> cross-head mix + head-LN -> P_lds -> barrier -> PV accumulate.
// f32 O-partials out (summed by k_osum). 2 blocks/CU co-resident
// (LDS 67.5KB <= 80KB, VGPR capped 128 by launch_bounds(512,4)) so one
// block's VALU mix fills the other's barrier/MFMA stalls.
// ---------------------------------------------------------------------------
__global__ __launch_bounds__(512, 4)
void k_fused(const short* __restrict__ Q, const short* __restrict__ Kb,
             const short* __restrict__ Vt, const float* __restrict__ zstat,
             const float* __restrict__ R, const float* __restrict__ rg,
             const float* __restrict__ rb, float* __restrict__ opart) {
    __shared__ short S_lds[8 * 32 * 64];  // [h][32i][64j] bf16, swz — 32 KB
    __shared__ short P_lds[8 * 32 * 64];  // [g][32i][64j] bf16, swz — 32 KB
    __shared__ float Rraw[64], Rc[64], rgs[8], rbs[8], zl[8 * 32];
    int b, i0, jh;
    decode_bid2(blockIdx.x, b, i0, jh);
    int tid = threadIdx.x, wv = tid >> 6, lane = tid & 63;
    int fr = lane & 15, fq = lane >> 4;
    if (tid < 64) Rraw[tid] = R[tid];
    if (tid < 8) { rgs[tid] = rg[tid]; rbs[tid] = rb[tid]; }
    if (tid >= 64 && tid < 320) {
        int q = tid - 64;
        zl[q] = zstat[(size_t)(b * 8 + (q >> 5)) * Nn + i0 + (q & 31)];
    }
    __syncthreads();
    if (tid < 64) {
        int h = tid >> 3;
        float mn = 0.f;
#pragma unroll
        for (int gg = 0; gg < 8; ++gg) mn += Rraw[h * 8 + gg];
        Rc[tid] = Rraw[tid] - mn * 0.125f;  // row-centered mix matrix
    }
    size_t bh = (size_t)(b * 8 + wv);
    const short* qb = Q + (bh * Nn + i0) * 64;
    bf16x8 qf[2][2];
#pragma unroll
    for (int in = 0; in < 2; ++in)
#pragma unroll
        for (int kk = 0; kk < 2; ++kk)
            qf[in][kk] = *(const bf16x8*)(qb + (in * 16 + fr) * 64 + kk * 32 + fq * 8);
    float zh[2] = {zl[wv * 32 + fr], zl[wv * 32 + 16 + fr]};
    const short* kbase = Kb + bh * Nn * 64 + (size_t)jh * 1024 * 64;
    const short* vbase = Vt + bh * 64 * Nn + (size_t)jh * 1024;
    const int mi = tid >> 4, j4 = (tid & 15) * 4;  // mix-phase ownership
    const int msw = (mi & 7) << 4;
    f32x4 acc_o[2][4] = {};
    for (int jt = 0; jt < 16; ++jt) {
        // ---- phase A: QK^T (swapped) + exp + S_lds write ----
        {
            const short* kb = kbase + jt * 64 * 64;
            f32x4 acc[4][2] = {};
#pragma unroll
            for (int kk = 0; kk < 2; ++kk)
#pragma unroll
                for (int jm = 0; jm < 4; ++jm) {
                    bf16x8 kf = *(const bf16x8*)(kb + (jm * 16 + fr) * 64 + kk * 32 + fq * 8);
                    acc[jm][0] = __builtin_amdgcn_mfma_f32_16x16x32_bf16(kf, qf[0][kk], acc[jm][0], 0, 0, 0);
                    acc[jm][1] = __builtin_amdgcn_mfma_f32_16x16x32_bf16(kf, qf[1][kk], acc[jm][1], 0, 0, 0);
                }
#pragma unroll
            for (int in = 0; in < 2; ++in) {
                int i = in * 16 + fr;
                int sw = (i & 7) << 4;
#pragma unroll
                for (int jm = 0; jm < 4; ++jm) {
                    bf16x4 pk;
#pragma unroll
                    for (int r = 0; r < 4; ++r)
                        pk[r] = f2bf(__expf(acc[jm][in][r] * 0.125f - zh[in]));
                    int j0 = jm * 16 + fq * 4;
                    *(bf16x4*)((char*)S_lds + wv * 4096 + i * 128 + ((j0 * 2) ^ sw)) = pk;
                }
            }
        }
        __syncthreads();
        // ---- phase B: cross-head mix + head-LN (one bf16x4 quad/thread) ----
        {
            bf16x4 sh[8];
#pragma unroll
            for (int h = 0; h < 8; ++h)
                sh[h] = *(const bf16x4*)((char*)S_lds + h * 4096 + mi * 128 + ((j4 * 2) ^ msw));
            bf16x4 og[8];
#pragma unroll
            for (int e = 0; e < 4; ++e) {
                float pv[8];
#pragma unroll
                for (int h = 0; h < 8; ++h) pv[h] = bf2f(sh[h][e]);
                float cc[8];
#pragma unroll
                for (int gg = 0; gg < 8; ++gg) {
                    float s = 0.f;
#pragma unroll
                    for (int h = 0; h < 8; ++h) s += pv[h] * Rc[h * 8 + gg];
                    cc[gg] = s;  // mean over gg is 0 by construction
                }
                float var = 0.f;
#pragma unroll
                for (int gg = 0; gg < 8; ++gg) var += cc[gg] * cc[gg];
                var *= 0.125f;
                float rs_ = rsqrtf(var + 1e-5f);
#pragma unroll
                for (int gg = 0; gg < 8; ++gg)
                    og[gg][e] = f2bf(cc[gg] * rs_ * rgs[gg] + rbs[gg]);
            }
#pragma unroll
            for (int gg = 0; gg < 8; ++gg)
                *(bf16x4*)((char*)P_lds + gg * 4096 + mi * 128 + ((j4 * 2) ^ msw)) = og[gg];
        }
        __syncthreads();
        // ---- phase C: PV for this wave's head g = wv ----
        {
            const short* vb = vbase + jt * 64;
#pragma unroll
            for (int kk = 0; kk < 2; ++kk) {
                bf16x8 vf[4];
#pragma unroll
                for (int dn = 0; dn < 4; ++dn)
                    vf[dn] = *(const bf16x8*)(vb + (size_t)(dn * 16 + fr) * Nn + kk * 32 + fq * 8);
#pragma unroll
                for (int im = 0; im < 2; ++im) {
                    int row = im * 16 + fr;
                    bf16x8 pa = *(const bf16x8*)((char*)P_lds + wv * 4096 + row * 128 +
                                                 (((kk * 32 + fq * 8) * 2) ^ ((row & 7) << 4)));
#pragma unroll
                    for (int dn = 0; dn < 4; ++dn)
                        acc_o[im][dn] = __builtin_amdgcn_mfma_f32_16x16x32_bf16(pa, vf[dn], acc_o[im][dn], 0, 0, 0);
                }
            }
        }
        __syncthreads();
    }
    float* po = opart + (size_t)jh * 4194304 + ((size_t)b * Nn + i0) * 512;
#pragma unroll
    for (int im = 0; im < 2; ++im)
#pragma unroll
        for (int dn = 0; dn < 4; ++dn)
#pragma unroll
            for (int r = 0; r < 4; ++r)
                po[(im * 16 + fq * 4 + r) * 512 + wv * 64 + dn * 16 + fr] = acc_o[im][dn][r];
}

// ---------------------------------------------------------------------------
// K5: sum the two j-half O partials -> outh bf16. 4,194,304 elements.
// ---------------------------------------------------------------------------
__global__ __launch_bounds__(256) void k_osum(const float* __restrict__ opart,
                                              short* __restrict__ outh) {
    int base = (blockIdx.x * 256 + threadIdx.x) * 4;
    f32x4 a = *(const f32x4*)(opart + base);
    f32x4 c = *(const f32x4*)(opart + 4194304 + base);
    bf16x4 o;
#pragma unroll
    for (int t = 0; t < 4; ++t) o[t] = f2bf(a[t] + c[t]);
    *(bf16x4*)(outh + base) = o;
}

extern "C" void kernel_launch(void* const* d_in, const int* in_sizes, int n_in,
                              void* d_out, int out_size, void* d_ws, size_t ws_size,
                              hipStream_t stream) {
    const float* x      = (const float*)d_in[0];
    const float* ln_g   = (const float*)d_in[1];
    const float* ln_b   = (const float*)d_in[2];
    const float* w_qkv  = (const float*)d_in[3];
    const float* reattn = (const float*)d_in[4];
    const float* rn_g   = (const float*)d_in[5];
    const float* rn_b   = (const float*)d_in[6];
    const float* w_out  = (const float*)d_in[7];
    const float* b_out  = (const float*)d_in[8];
    float* out = (float*)d_out;

    char* ws = (char*)d_ws;
    short* wqkvT = (short*)ws; ws += (size_t)1536 * 512 * 2;
    short* woutT = (short*)ws; ws += (size_t)512 * 512 * 2;
    short* xn    = (short*)ws; ws += (size_t)8192 * 512 * 2;   // dead after k_qkv
    short* Q     = (short*)ws; ws += (size_t)32 * 2048 * 64 * 2;
    short* Kb    = (short*)ws; ws += (size_t)32 * 2048 * 64 * 2;
    short* Vt    = (short*)ws; ws += (size_t)32 * 64 * 2048 * 2;
    short* outh  = (short*)ws; ws += (size_t)8192 * 512 * 2;
    float* opart = (float*)ws; ws += (size_t)2 * 4194304 * 4;  // 33.6 MB
    float* mpart = (float*)ws; ws += (size_t)2 * 65536 * 4;
    float* lpart = (float*)ws; ws += (size_t)2 * 65536 * 4;
    // zh stats alias the dead xn region (65536*4 = 256 KB << 8.39 MB)
    float* zstat = (float*)xn;

    k_transpose_cast<<<(512 * 1536 + 255) / 256, 256, 0, stream>>>(w_qkv, wqkvT, 512, 1536);
    k_transpose_cast<<<(512 * 512 + 255) / 256, 256, 0, stream>>>(w_out, woutT, 512, 512);
    k_ln<<<8192 / 4, 256, 0, stream>>>(x, ln_g, ln_b, xn);
    k_qkv<<<dim3(8192 / 128, 1536 / 128), 256, 0, stream>>>(xn, wqkvT, Q, Kb, Vt);

    k_stats<<<512, 512, 0, stream>>>(Q, Kb, mpart, lpart);
    k_zcomb<<<256, 256, 0, stream>>>(mpart, lpart, zstat);
    k_fused<<<512, 512, 0, stream>>>(Q, Kb, Vt, zstat, reattn, rn_g, rn_b, opart);
    k_osum<<<4096, 256, 0, stream>>>(opart, outh);

    k_out<<<dim3(8192 / 128, 512 / 128), 256, 0, stream>>>(outh, woutT, b_out, out);
}

// Round 10
// 341.763 us; speedup vs baseline: 1.6673x; 1.0004x over previous
//
#include <hip/hip_runtime.h>
#include <hip/hip_bf16.h>
#include <math.h>

#define DEV __device__ __forceinline__

typedef short bf16x8 __attribute__((ext_vector_type(8)));
typedef short bf16x4 __attribute__((ext_vector_type(4)));
typedef float f32x4 __attribute__((ext_vector_type(4)));

static const int Nn = 2048;
static const int DIMd = 512;

DEV float bf2f(short u) {
    union { unsigned int i; float f; } c;
    c.i = ((unsigned int)(unsigned short)u) << 16;
    return c.f;
}

DEV short f2bf(float f) {
    union { float f; unsigned int i; } c;
    c.f = f;
    unsigned int u = c.i;
    unsigned int r = (u + 0x7fffu + ((u >> 16) & 1u)) >> 16;
    return (short)r;
}

// async global->LDS, 16B per lane (lane-linear LDS dest required)
DEV void gload16(const short* __restrict__ g, short* l) {
    __builtin_amdgcn_global_load_lds(
        (__attribute__((address_space(1))) void*)g,
        (__attribute__((address_space(3))) void*)l, 16, 0, 0);
}

// ---------------------------------------------------------------------------
// K0: transpose + cast f32 [K][N] -> bf16 [N][K]
// ---------------------------------------------------------------------------
__global__ void k_transpose_cast(const float* __restrict__ src,
                                 short* __restrict__ dst, int K, int N) {
    int o = blockIdx.x * 256 + threadIdx.x;
    if (o >= K * N) return;
    int n = o / K, k = o - n * K;
    dst[o] = f2bf(src[(size_t)k * N + n]);
}

// ---------------------------------------------------------------------------
// K1: row LayerNorm over DIM=512, f32 in -> bf16 out. One wave per row.
// ---------------------------------------------------------------------------
__global__ __launch_bounds__(256) void k_ln(const float* __restrict__ x,
                                            const float* __restrict__ g,
                                            const float* __restrict__ bta,
                                            short* __restrict__ xn) {
    int row = blockIdx.x * 4 + (threadIdx.x >> 6);
    int lane = threadIdx.x & 63;
    const float* xr = x + (size_t)row * DIMd;
    float4 v0 = ((const float4*)xr)[lane * 2];
    float4 v1 = ((const float4*)xr)[lane * 2 + 1];
    float f[8] = {v0.x, v0.y, v0.z, v0.w, v1.x, v1.y, v1.z, v1.w};
    float s = 0.f, sq = 0.f;
#pragma unroll
    for (int t = 0; t < 8; ++t) { s += f[t]; sq += f[t] * f[t]; }
#pragma unroll
    for (int off = 32; off >= 1; off >>= 1) {
        s += __shfl_xor(s, off);
        sq += __shfl_xor(sq, off);
    }
    float mu = s * (1.0f / 512.0f);
    float var = sq * (1.0f / 512.0f) - mu * mu;
    float rs = rsqrtf(var + 1e-5f);
    bf16x8 o;
#pragma unroll
    for (int t = 0; t < 8; ++t) {
        int c = lane * 8 + t;
        o[t] = f2bf((f[t] - mu) * rs * g[c] + bta[c]);
    }
    *(bf16x8*)(xn + (size_t)row * DIMd + lane * 8) = o;
}

// ---------------------------------------------------------------------------
// m97-style 128x128 tile GEMM main loop (A [M][K], B^T [N][K], k-contig).
// ---------------------------------------------------------------------------
DEV void gemm128_loop(const short* __restrict__ A, const short* __restrict__ B,
                      int K, int i0, int n0, int tid,
                      short* As, short* Bs, f32x4 acc[4][4]) {
    const int w = tid >> 6, wr = w >> 1, wc = w & 1;
    const int lane = tid & 63, fr = lane & 15, fq = lane >> 4;
    const int sr = tid >> 3, sc = (tid & 7) * 8;
    for (int k0 = 0; k0 < K; k0 += 64) {
#pragma unroll
        for (int L = 0; L < 4; ++L) {
            gload16(A + (size_t)(i0 + L * 32 + sr) * K + k0 + sc,
                    As + (L * 32 + sr) * 64 + sc);
            gload16(B + (size_t)(n0 + L * 32 + sr) * K + k0 + sc,
                    Bs + (L * 32 + sr) * 64 + sc);
        }
        __syncthreads();
#pragma unroll
        for (int kk = 0; kk < 2; ++kk) {
            bf16x8 af[4], bfr[4];
#pragma unroll
            for (int m = 0; m < 4; ++m)
                af[m] = *(const bf16x8*)(As + (wr * 64 + m * 16 + fr) * 64 + kk * 32 + fq * 8);
#pragma unroll
            for (int n = 0; n < 4; ++n)
                bfr[n] = *(const bf16x8*)(Bs + (wc * 64 + n * 16 + fr) * 64 + kk * 32 + fq * 8);
#pragma unroll
            for (int m = 0; m < 4; ++m)
#pragma unroll
                for (int n = 0; n < 4; ++n)
                    acc[m][n] = __builtin_amdgcn_mfma_f32_16x16x32_bf16(af[m], bfr[n], acc[m][n], 0, 0, 0);
        }
        __syncthreads();
    }
}

// ---------------------------------------------------------------------------
// K2: qkv = xn @ w_qkvT^T. Scatter epilogue into Q, K (k-contig) and Vt.
// ---------------------------------------------------------------------------
__global__ __launch_bounds__(256) void k_qkv(const short* __restrict__ xn,
                                             const short* __restrict__ wT,
                                             short* __restrict__ Q,
                                             short* __restrict__ Kb,
                                             short* __restrict__ Vt) {
    __shared__ short As[128 * 64], Bs[128 * 64];
    int tid = threadIdx.x;
    int i0 = blockIdx.x * 128, n0 = blockIdx.y * 128;
    f32x4 acc[4][4] = {};
    gemm128_loop(xn, wT, DIMd, i0, n0, tid, As, Bs, acc);
    const int w = tid >> 6, wr = w >> 1, wc = w & 1;
    const int lane = tid & 63, fr = lane & 15, fq = lane >> 4;
#pragma unroll
    for (int m = 0; m < 4; ++m) {
#pragma unroll
        for (int n = 0; n < 4; ++n) {
#pragma unroll
            for (int r = 0; r < 4; ++r) {
                int row = i0 + wr * 64 + m * 16 + fq * 4 + r;
                int c = n0 + wc * 64 + n * 16 + fr;
                short hv = f2bf(acc[m][n][r]);
                int b = row >> 11, i = row & 2047;
                int t = c >> 9, rem = c & 511;
                int h = rem >> 6, dd = rem & 63;
                size_t bh = (size_t)(b * 8 + h);
                if (t == 0)      Q [(bh * Nn + i) * 64 + dd] = hv;
                else if (t == 1) Kb[(bh * Nn + i) * 64 + dd] = hv;
                else             Vt[(bh * 64 + dd) * Nn + i] = hv;
            }
        }
    }
}

// ---------------------------------------------------------------------------
// K6: final = out_h @ w_outT^T + b_out. f32 out.
// ---------------------------------------------------------------------------
__global__ __launch_bounds__(256) void k_out(const short* __restrict__ outh,
                                             const short* __restrict__ wT,
                                             const float* __restrict__ bias,
                                             float* __restrict__ out) {
    __shared__ short As[128 * 64], Bs[128 * 64];
    int tid = threadIdx.x;
    int i0 = blockIdx.x * 128, n0 = blockIdx.y * 128;
    f32x4 acc[4][4] = {};
    gemm128_loop(outh, wT, 512, i0, n0, tid, As, Bs, acc);
    const int w = tid >> 6, wr = w >> 1, wc = w & 1;
    const int lane = tid & 63, fr = lane & 15, fq = lane >> 4;
#pragma unroll
    for (int m = 0; m < 4; ++m)
#pragma unroll
        for (int n = 0; n < 4; ++n)
#pragma unroll
            for (int r = 0; r < 4; ++r) {
                int row = i0 + wr * 64 + m * 16 + fq * 4 + r;
                int c = n0 + wc * 64 + n * 16 + fr;
                out[(size_t)row * 512 + c] = acc[m][n][r] + bias[c];
            }
}

// XCD-aware decode of a 512-block 1-D grid into (b, i0, jh). Blocks sharing
// (b, jh) land on one XCD => that XCD's L2 holds one K/V half-panel (~2 MB).
DEV void decode_bid2(int bid, int& b, int& i0, int& jh) {
    int xcd = bid & 7, slot = bid >> 3;  // slot 0..63
    b = xcd >> 1;
    jh = xcd & 1;
    i0 = slot * 32;
}

// ---------------------------------------------------------------------------
// K3a: stats partials. Block = (b, i0, jh); wave h owns head h, 32 q-rows,
// 1024 j (16 jt). Swapped QK^T. Writes partial (m, l) per (bh, i).
// waves_per_eu(4,4): pin 4 waves/EU exactly -> 128 VGPR cap, no 64-VGPR
// spill heuristics (round-9 lesson).
// ---------------------------------------------------------------------------
__global__ __launch_bounds__(512)
__attribute__((amdgpu_waves_per_eu(4, 4)))
void k_stats(const short* __restrict__ Q,
             const short* __restrict__ Kb,
             float* __restrict__ mpart,
             float* __restrict__ lpart) {
    int b, i0, jh;
    decode_bid2(blockIdx.x, b, i0, jh);
    int tid = threadIdx.x, wv = tid >> 6, lane = tid & 63;
    int fr = lane & 15, fq = lane >> 4;
    size_t bh = (size_t)(b * 8 + wv);
    const short* qb = Q + (bh * Nn + i0) * 64;
    bf16x8 qf[2][2];
#pragma unroll
    for (int in = 0; in < 2; ++in)
#pragma unroll
        for (int kk = 0; kk < 2; ++kk)
            qf[in][kk] = *(const bf16x8*)(qb + (in * 16 + fr) * 64 + kk * 32 + fq * 8);
    float m[2] = {-1e30f, -1e30f}, l[2] = {0.f, 0.f};
    const short* kbase = Kb + bh * Nn * 64 + (size_t)jh * 1024 * 64;
    for (int jt = 0; jt < 16; ++jt) {
        const short* kb = kbase + jt * 64 * 64;
        f32x4 acc[4][2] = {};
#pragma unroll
        for (int kk = 0; kk < 2; ++kk)
#pragma unroll
            for (int jm = 0; jm < 4; ++jm) {
                bf16x8 kf = *(const bf16x8*)(kb + (jm * 16 + fr) * 64 + kk * 32 + fq * 8);
                acc[jm][0] = __builtin_amdgcn_mfma_f32_16x16x32_bf16(kf, qf[0][kk], acc[jm][0], 0, 0, 0);
                acc[jm][1] = __builtin_amdgcn_mfma_f32_16x16x32_bf16(kf, qf[1][kk], acc[jm][1], 0, 0, 0);
            }
#pragma unroll
        for (int in = 0; in < 2; ++in) {
            float mt = acc[0][in][0];
#pragma unroll
            for (int jm = 0; jm < 4; ++jm)
#pragma unroll
                for (int r = 0; r < 4; ++r) mt = fmaxf(mt, acc[jm][in][r]);
            mt = fmaxf(mt, __shfl_xor(mt, 16));
            mt = fmaxf(mt, __shfl_xor(mt, 32));
            float es = 0.f;
#pragma unroll
            for (int jm = 0; jm < 4; ++jm)
#pragma unroll
                for (int r = 0; r < 4; ++r)
                    es += __expf((acc[jm][in][r] - mt) * 0.125f);
            es += __shfl_xor(es, 16);
            es += __shfl_xor(es, 32);
            float mn = fmaxf(m[in], mt);
            l[in] = l[in] * __expf((m[in] - mn) * 0.125f) + es * __expf((mt - mn) * 0.125f);
            m[in] = mn;
        }
    }
    if (fq == 0) {
#pragma unroll
        for (int in = 0; in < 2; ++in) {
            size_t o = (size_t)jh * 65536 + bh * Nn + i0 + in * 16 + fr;
            mpart[o] = m[in];
            lpart[o] = l[in];
        }
    }
}

// ---------------------------------------------------------------------------
// K3b: combine the two j-half stats -> zh = m*scale + log(l). 65536 elems.
// ---------------------------------------------------------------------------
__global__ __launch_bounds__(256) void k_zcomb(const float* __restrict__ mpart,
                                               const float* __restrict__ lpart,
                                               float* __restrict__ zstat) {
    int idx = blockIdx.x * 256 + threadIdx.x;
    float m0 = mpart[idx], m1 = mpart[65536 + idx];
    float l0 = lpart[idx], l1 = lpart[65536 + idx];
    float M = fmaxf(m0, m1);
    float L = l0 * __expf((m0 - M) * 0.125f) + l1 * __expf((m1 - M) * 0.125f);
    zstat[idx] = M * 0.125f + __logf(L);
}

// ---------------------------------------------------------------------------
// K4: fully fused pass, split-j. Block = (b, 32 i-rows, jh); 16 jt.
// Per jt: recompute QK^T (swapped) -> p=exp(s-zh) -> S_lds (swz) -> barrier
// -> cross-head mix + head-LN -> P_lds -> barrier -> PV accumulate.
// waves_per_eu(4,4): exactly 4 waves/EU => 128-VGPR cap (state fits, round 8
// proved no spill at 128) AND 2 blocks/CU co-residency (LDS 67.5KB).
// Round-9 lesson: launch_bounds(512,4) min alone let the allocator target
// 8 waves/EU (64 VGPR) and spill ~half the live set to scratch.
// ---------------------------------------------------------------------------
__global__ __launch_bounds__(512)
__attribute__((amdgpu_waves_per_eu(4, 4)))
void k_fused(const short* __restrict__ Q, const short* __restrict__ Kb,
             const short* __restrict__ Vt, const float* __restrict__ zstat,
             const float* __restrict__ R, const float* __restrict__ rg,
             const float* __restrict__ rb, float* __restrict__ opart) {
    __shared__ short S_lds[8 * 32 * 64];  // [h][32i][64j] bf16, swz — 32 KB
    __shared__ short P_lds[8 * 32 * 64];  // [g][32i][64j] bf16, swz — 32 KB
    __shared__ float Rraw[64], Rc[64], rgs[8], rbs[8], zl[8 * 32];
    int b, i0, jh;
    decode_bid2(blockIdx.x, b, i0, jh);
    int tid = threadIdx.x, wv = tid >> 6, lane = tid & 63;
    int fr = lane & 15, fq = lane >> 4;
    if (tid < 64) Rraw[tid] = R[tid];
    if (tid < 8) { rgs[tid] = rg[tid]; rbs[tid] = rb[tid]; }
    if (tid >= 64 && tid < 320) {
        int q = tid - 64;
        zl[q] = zstat[(size_t)(b * 8 + (q >> 5)) * Nn + i0 + (q & 31)];
    }
    __syncthreads();
    if (tid < 64) {
        int h = tid >> 3;
        float mn = 0.f;
#pragma unroll
        for (int gg = 0; gg < 8; ++gg) mn += Rraw[h * 8 + gg];
        Rc[tid] = Rraw[tid] - mn * 0.125f;  // row-centered mix matrix
    }
    size_t bh = (size_t)(b * 8 + wv);
    const short* qb = Q + (bh * Nn + i0) * 64;
    bf16x8 qf[2][2];
#pragma unroll
    for (int in = 0; in < 2; ++in)
#pragma unroll
        for (int kk = 0; kk < 2; ++kk)
            qf[in][kk] = *(const bf16x8*)(qb + (in * 16 + fr) * 64 + kk * 32 + fq * 8);
    float zh[2] = {zl[wv * 32 + fr], zl[wv * 32 + 16 + fr]};
    const short* kbase = Kb + bh * Nn * 64 + (size_t)jh * 1024 * 64;
    const short* vbase = Vt + bh * 64 * Nn + (size_t)jh * 1024;
    const int mi = tid >> 4, j4 = (tid & 15) * 4;  // mix-phase ownership
    const int msw = (mi & 7) << 4;
    f32x4 acc_o[2][4] = {};
    for (int jt = 0; jt < 16; ++jt) {
        // ---- phase A: QK^T (swapped) + exp + S_lds write ----
        {
            const short* kb = kbase + jt * 64 * 64;
            f32x4 acc[4][2] = {};
#pragma unroll
            for (int kk = 0; kk < 2; ++kk)
#pragma unroll
                for (int jm = 0; jm < 4; ++jm) {
                    bf16x8 kf = *(const bf16x8*)(kb + (jm * 16 + fr) * 64 + kk * 32 + fq * 8);
                    acc[jm][0] = __builtin_amdgcn_mfma_f32_16x16x32_bf16(kf, qf[0][kk], acc[jm][0], 0, 0, 0);
                    acc[jm][1] = __builtin_amdgcn_mfma_f32_16x16x32_bf16(kf, qf[1][kk], acc[jm][1], 0, 0, 0);
                }
#pragma unroll
            for (int in = 0; in < 2; ++in) {
                int i = in * 16 + fr;
                int sw = (i & 7) << 4;
#pragma unroll
                for (int jm = 0; jm < 4; ++jm) {
                    bf16x4 pk;
#pragma unroll
                    for (int r = 0; r < 4; ++r)
                        pk[r] = f2bf(__expf(acc[jm][in][r] * 0.125f - zh[in]));
                    int j0 = jm * 16 + fq * 4;
                    *(bf16x4*)((char*)S_lds + wv * 4096 + i * 128 + ((j0 * 2) ^ sw)) = pk;
                }
            }
        }
        __syncthreads();
        // ---- phase B: cross-head mix + head-LN (one bf16x4 quad/thread) ----
        {
            bf16x4 sh[8];
#pragma unroll
            for (int h = 0; h < 8; ++h)
                sh[h] = *(const bf16x4*)((char*)S_lds + h * 4096 + mi * 128 + ((j4 * 2) ^ msw));
            bf16x4 og[8];
#pragma unroll
            for (int e = 0; e < 4; ++e) {
                float pv[8];
#pragma unroll
                for (int h = 0; h < 8; ++h) pv[h] = bf2f(sh[h][e]);
                float cc[8];
#pragma unroll
                for (int gg = 0; gg < 8; ++gg) {
                    float s = 0.f;
#pragma unroll
                    for (int h = 0; h < 8; ++h) s += pv[h] * Rc[h * 8 + gg];
                    cc[gg] = s;  // mean over gg is 0 by construction
                }
                float var = 0.f;
#pragma unroll
                for (int gg = 0; gg < 8; ++gg) var += cc[gg] * cc[gg];
                var *= 0.125f;
                float rs_ = rsqrtf(var + 1e-5f);
#pragma unroll
                for (int gg = 0; gg < 8; ++gg)
                    og[gg][e] = f2bf(cc[gg] * rs_ * rgs[gg] + rbs[gg]);
            }
#pragma unroll
            for (int gg = 0; gg < 8; ++gg)
                *(bf16x4*)((char*)P_lds + gg * 4096 + mi * 128 + ((j4 * 2) ^ msw)) = og[gg];
        }
        __syncthreads();
        // ---- phase C: PV for this wave's head g = wv ----
        {
            const short* vb = vbase + jt * 64;
#pragma unroll
            for (int kk = 0; kk < 2; ++kk) {
                bf16x8 vf[4];
#pragma unroll
                for (int dn = 0; dn < 4; ++dn)
                    vf[dn] = *(const bf16x8*)(vb + (size_t)(dn * 16 + fr) * Nn + kk * 32 + fq * 8);
#pragma unroll
                for (int im = 0; im < 2; ++im) {
                    int row = im * 16 + fr;
                    bf16x8 pa = *(const bf16x8*)((char*)P_lds + wv * 4096 + row * 128 +
                                                 (((kk * 32 + fq * 8) * 2) ^ ((row & 7) << 4)));
#pragma unroll
                    for (int dn = 0; dn < 4; ++dn)
                        acc_o[im][dn] = __builtin_amdgcn_mfma_f32_16x16x32_bf16(pa, vf[dn], acc_o[im][dn], 0, 0, 0);
                }
            }
        }
        __syncthreads();
    }
    float* po = opart + (size_t)jh * 4194304 + ((size_t)b * Nn + i0) * 512;
#pragma unroll
    for (int im = 0; im < 2; ++im)
#pragma unroll
        for (int dn = 0; dn < 4; ++dn)
#pragma unroll
            for (int r = 0; r < 4; ++r)
                po[(im * 16 + fq * 4 + r) * 512 + wv * 64 + dn * 16 + fr] = acc_o[im][dn][r];
}

// ---------------------------------------------------------------------------
// K5: sum the two j-half O partials -> outh bf16. 4,194,304 elements.
// ---------------------------------------------------------------------------
__global__ __launch_bounds__(256) void k_osum(const float* __restrict__ opart,
                                              short* __restrict__ outh) {
    int base = (blockIdx.x * 256 + threadIdx.x) * 4;
    f32x4 a = *(const f32x4*)(opart + base);
    f32x4 c = *(const f32x4*)(opart + 4194304 + base);
    bf16x4 o;
#pragma unroll
    for (int t = 0; t < 4; ++t) o[t] = f2bf(a[t] + c[t]);
    *(bf16x4*)(outh + base) = o;
}

extern "C" void kernel_launch(void* const* d_in, const int* in_sizes, int n_in,
                              void* d_out, int out_size, void* d_ws, size_t ws_size,
                              hipStream_t stream) {
    const float* x      = (const float*)d_in[0];
    const float* ln_g   = (const float*)d_in[1];
    const float* ln_b   = (const float*)d_in[2];
    const float* w_qkv  = (const float*)d_in[3];
    const float* reattn = (const float*)d_in[4];
    const float* rn_g   = (const float*)d_in[5];
    const float* rn_b   = (const float*)d_in[6];
    const float* w_out  = (const float*)d_in[7];
    const float* b_out  = (const float*)d_in[8];
    float* out = (float*)d_out;

    char* ws = (char*)d_ws;
    short* wqkvT = (short*)ws; ws += (size_t)1536 * 512 * 2;
    short* woutT = (short*)ws; ws += (size_t)512 * 512 * 2;
    short* xn    = (short*)ws; ws += (size_t)8192 * 512 * 2;   // dead after k_qkv
    short* Q     = (short*)ws; ws += (size_t)32 * 2048 * 64 * 2;
    short* Kb    = (short*)ws; ws += (size_t)32 * 2048 * 64 * 2;
    short* Vt    = (short*)ws; ws += (size_t)32 * 64 * 2048 * 2;
    short* outh  = (short*)ws; ws += (size_t)8192 * 512 * 2;
    float* opart = (float*)ws; ws += (size_t)2 * 4194304 * 4;  // 33.6 MB
    float* mpart = (float*)ws; ws += (size_t)2 * 65536 * 4;
    float* lpart = (float*)ws; ws += (size_t)2 * 65536 * 4;
    // zh stats alias the dead xn region (65536*4 = 256 KB << 8.39 MB)
    float* zstat = (float*)xn;

    k_transpose_cast<<<(512 * 1536 + 255) / 256, 256, 0, stream>>>(w_qkv, wqkvT, 512, 1536);
    k_transpose_cast<<<(512 * 512 + 255) / 256, 256, 0, stream>>>(w_out, woutT, 512, 512);
    k_ln<<<8192 / 4, 256, 0, stream>>>(x, ln_g, ln_b, xn);
    k_qkv<<<dim3(8192 / 128, 1536 / 128), 256, 0, stream>>>(xn, wqkvT, Q, Kb, Vt);

    k_stats<<<512, 512, 0, stream>>>(Q, Kb, mpart, lpart);
    k_zcomb<<<256, 256, 0, stream>>>(mpart, lpart, zstat);
    k_fused<<<512, 512, 0, stream>>>(Q, Kb, Vt, zstat, reattn, rn_g, rn_b, opart);
    k_osum<<<4096, 256, 0, stream>>>(opart, outh);

    k_out<<<dim3(8192 / 128, 512 / 128), 256, 0, stream>>>(outh, woutT, b_out, out);
}